// Round 1
// 7871.175 us; speedup vs baseline: 1.2231x; 1.2231x over previous
//
#include <hip/hip_runtime.h>
#include <cmath>

#define NHID 1024
#define NTOK 10000
#define TT 128
#define BB 32
#define BN (BB*NHID)            // elems per (B,NHID) state
#define WMAT (2048*1024)        // elems per transposed weight matrix

typedef __attribute__((ext_vector_type(8))) short s8v;   // 8 x bf16 raw
typedef __attribute__((ext_vector_type(4))) float f4v;   // MFMA accumulator

#define MFMA(a,b,c) __builtin_amdgcn_mfma_f32_16x16x32_bf16(a,b,c,0,0,0)

__device__ __forceinline__ float sigf(float x){ return 1.f/(1.f+__expf(-x)); }
__device__ __forceinline__ float actf(int a, float h){
  switch(a){ case 0: return sigf(h); case 1: return fmaxf(h,0.f);
             case 2: return tanhf(h); default: return h; }
}
__device__ __forceinline__ unsigned short f2bf(float x){
  union { float f; unsigned u; } v; v.f = x;
  unsigned r = v.u + 0x7fffu + ((v.u >> 16) & 1u);
  return (unsigned short)(r >> 16);
}

// ---------------- prep kernels ----------------

__global__ __launch_bounds__(256) void k_transpose_cvt(
    const float* __restrict__ W0, const float* __restrict__ Ws,
    unsigned short* __restrict__ dstAll)
{
  int z = blockIdx.z;
  const float* src = (z==0) ? W0 : (z==1) ? (W0 + (size_t)1024*2048)
                                          : (Ws + (size_t)(z-2)*1024*2048);
  unsigned short* dst = dstAll + (size_t)z*WMAT;
  __shared__ float tile[32][33];
  int n0 = blockIdx.x*32;
  int k0 = blockIdx.y*32;
  int tx = threadIdx.x & 31, ty = threadIdx.x >> 5;
  #pragma unroll
  for (int i=0;i<4;i++){
    int k = k0 + ty + i*8;
    tile[ty + i*8][tx] = src[(size_t)k*2048 + n0 + tx];
  }
  __syncthreads();
  #pragma unroll
  for (int i=0;i<4;i++){
    int n = n0 + ty + i*8;
    dst[(size_t)n*1024 + k0 + tx] = f2bf(tile[tx][ty + i*8]);
  }
}

__global__ void k_cvt(const float* __restrict__ src, unsigned short* __restrict__ dst, int n){
  int i = blockIdx.x*blockDim.x + threadIdx.x;
  int stride = gridDim.x*blockDim.x;
  for (; i < n; i += stride) dst[i] = f2bf(src[i]);
}

__global__ void k_zero(unsigned* __restrict__ p){
  if (threadIdx.x < 16) p[threadIdx.x] = 0u;
}

// ---------------- persistent recurrence kernel ----------------
// grid = 256 WGs x 256 threads (4 waves), 1 per CU, all co-resident.
// counters: cnt[s] = #tiles of state s written (monotonic over steps); cnt[8] = h.
// KEY CHANGE vs prev version: all weight B-tiles live in VGPRs (loaded once
// before the t-loop). The per-hop agent-acquire invalidates L2, so any B kept
// in cache was refetched from L3 every barrier (26 MB/step in FETCH_SIZE).
// Registers are immune to cache invalidation.

__device__ __forceinline__ void wg_wait(unsigned* c, unsigned target){
  if (threadIdx.x == 0) {
    while (__hip_atomic_load(c, __ATOMIC_RELAXED, __HIP_MEMORY_SCOPE_AGENT) < target)
      __builtin_amdgcn_s_sleep(1);
    (void)__hip_atomic_load(c, __ATOMIC_ACQUIRE, __HIP_MEMORY_SCOPE_AGENT); // inv L1/L2
  }
  __syncthreads();
}
__device__ __forceinline__ void wg_signal(unsigned* c){
  __syncthreads();   // per-wave vmcnt(0) drain before barrier => stores visible
  if (threadIdx.x == 0)
    __hip_atomic_fetch_add(c, 1u, __ATOMIC_RELEASE, __HIP_MEMORY_SCOPE_AGENT);
}

struct B8  { s8v c[8];  s8v h[8];  };   //  64 VGPRs: one edge task, K=256/wave
struct B16 { s8v c[16]; s8v h[16]; };   // 128 VGPRs: L1 (K=512/wave)

__device__ __forceinline__ void load_b8(const unsigned short* __restrict__ Wt,
                                        int z, int j0, int r, int kb, int q, B8& B){
  const unsigned short* wz = Wt + (size_t)z*WMAT;
  const s8v* bc = (const s8v*)(wz + (size_t)(j0+r)*1024 + kb);
  const s8v* bh = (const s8v*)(wz + (size_t)(1024+j0+r)*1024 + kb);
  #pragma unroll
  for (int i=0;i<8;i++){ B.c[i]=bc[q+4*i]; B.h[i]=bh[q+4*i]; }
}

// one edge task with weights in registers: 16 paired cols (tile j0),
// K=1024 split 4 ways over waves
__device__ __forceinline__ void do_edge_reg(
    const B8& B, float* __restrict__ st_f,
    unsigned short* __restrict__ st_bf, float* __restrict__ red,
    unsigned* __restrict__ cnt, int pred, int outs, int act,
    int j0, unsigned target, int wave, int q, int r, int tid)
{
  wg_wait(&cnt[pred], target);
  const unsigned short* spb = st_bf + (size_t)pred*BN;
  int kb = wave*256;
  const s8v* ap0 = (const s8v*)(spb + (size_t)r*NHID + kb);
  const s8v* ap1 = (const s8v*)(spb + (size_t)(16+r)*NHID + kb);
  f4v zz = {0.f,0.f,0.f,0.f};
  f4v aC0=zz,aC1=zz,aH0=zz,aH1=zz;
  #pragma unroll
  for (int i=0;i<8;i++){
    s8v a0=ap0[q+4*i], a1=ap1[q+4*i];
    aC0=MFMA(a0,B.c[i],aC0); aC1=MFMA(a1,B.c[i],aC1);
    aH0=MFMA(a0,B.h[i],aH0); aH1=MFMA(a1,B.h[i],aH1);
  }
  #pragma unroll
  for (int i=0;i<4;i++){
    red[((wave*4+0)*32 + q*4+i)*16 + r]    = aC0[i];
    red[((wave*4+0)*32 + 16+q*4+i)*16 + r] = aC1[i];
    red[((wave*4+1)*32 + q*4+i)*16 + r]    = aH0[i];
    red[((wave*4+1)*32 + 16+q*4+i)*16 + r] = aH1[i];
  }
  __syncthreads();
  int row = tid>>3, col = (tid&7)*2;
  float cs0=0,cs1=0,hs0=0,hs1=0;
  #pragma unroll
  for (int w2=0; w2<4; w2++){
    cs0 += red[((w2*4+0)*32+row)*16+col];
    cs1 += red[((w2*4+0)*32+row)*16+col+1];
    hs0 += red[((w2*4+1)*32+row)*16+col];
    hs1 += red[((w2*4+1)*32+row)*16+col+1];
  }
  size_t off = (size_t)row*NHID + j0 + col;
  const float* spf = st_f + (size_t)pred*BN;
  float sp0 = spf[off], sp1 = spf[off+1];
  float v0 = sp0 + sigf(cs0)*(actf(act,hs0) - sp0);
  float v1 = sp1 + sigf(cs1)*(actf(act,hs1) - sp1);
  __hip_atomic_store(&st_f[(size_t)outs*BN+off],   v0, __ATOMIC_RELAXED, __HIP_MEMORY_SCOPE_AGENT);
  __hip_atomic_store(&st_f[(size_t)outs*BN+off+1], v1, __ATOMIC_RELAXED, __HIP_MEMORY_SCOPE_AGENT);
  unsigned pk = (unsigned)f2bf(v0) | ((unsigned)f2bf(v1)<<16);
  __hip_atomic_store((unsigned*)(st_bf + (size_t)outs*BN + off), pk,
                     __ATOMIC_RELAXED, __HIP_MEMORY_SCOPE_AGENT);
  wg_signal(&cnt[outs]);
}

__global__ __launch_bounds__(256, 1) void k_recur(
    const int* __restrict__ tok, const float* __restrict__ h0f,
    const unsigned short* __restrict__ encb,
    const unsigned short* __restrict__ Wt,
    const unsigned short* __restrict__ h0b,
    float* __restrict__ st_f, unsigned short* __restrict__ st_bf,
    float* __restrict__ h_f, unsigned short* __restrict__ h_bf,
    unsigned short* __restrict__ hid_bf, unsigned* __restrict__ cnt)
{
  __shared__ float red[4*4*32*16];   // 32 KB: [wave][ch up to 4][row 32][col 16]
  int wg = blockIdx.x, grp = wg >> 6, tile = wg & 63;
  int tid = threadIdx.x, wave = tid>>6, lane = tid&63, q = lane>>4, r = lane&15;
  int j0 = tile * 16;

  if (grp == 0) {
    // ---- weights resident in VGPRs for the whole kernel ----
    B16 BL;   // L1 init matmul; wave-specific K-chunk of the 2048-deep W0
    {
      const unsigned short* wz = Wt + (size_t)(wave>>1)*WMAT;
      int kloc = (wave & 1) * 512;
      const s8v* bc = (const s8v*)(wz + (size_t)(j0+r)*1024 + kloc);
      const s8v* bh = (const s8v*)(wz + (size_t)(1024+j0+r)*1024 + kloc);
      #pragma unroll
      for (int i=0;i<16;i++){ BL.c[i]=bc[q+4*i]; BL.h[i]=bh[q+4*i]; }
    }
    B8 B3; load_b8(Wt, 5, j0, r, wave*256, q, B3);   // e3: identity, s1->s4

    for (int t = 0; t < TT; ++t) {
      unsigned tgt = 64u*(t+1);
      // ---- L1: init (K=2048: waves 0-1 take x half, 2-3 take h half) ----
      // Prefetch the static x-half A-operand BEFORE waiting on h(t-1):
      // embedding rows depend only on tokens, so their L3 latency hides
      // under the cnt[8] poll.
      s8v xa0[16], xa1[16];
      if (wave < 2){
        int kb = wave * 512;
        const s8v* ap0 = (const s8v*)(encb + (size_t)tok[t*BB + r]*NHID + kb);
        const s8v* ap1 = (const s8v*)(encb + (size_t)tok[t*BB + 16 + r]*NHID + kb);
        #pragma unroll
        for (int i=0;i<16;i++){ xa0[i]=ap0[q+4*i]; xa1[i]=ap1[q+4*i]; }
      }
      if (t) wg_wait(&cnt[8], 64u*t);
      {
        f4v zz = {0.f,0.f,0.f,0.f};
        f4v aC0=zz,aC1=zz,aH0=zz,aH1=zz;
        if (wave < 2) {
          #pragma unroll
          for (int i=0;i<16;i++){
            s8v a0=xa0[i], a1=xa1[i];
            aC0=MFMA(a0,BL.c[i],aC0); aC1=MFMA(a1,BL.c[i],aC1);
            aH0=MFMA(a0,BL.h[i],aH0); aH1=MFMA(a1,BL.h[i],aH1);
          }
        } else {
          const unsigned short* hb = t ? h_bf : h0b;
          int kb = (wave-2)*512;
          const s8v* ap0 = (const s8v*)(hb + (size_t)r*NHID + kb);
          const s8v* ap1 = (const s8v*)(hb + (size_t)(16+r)*NHID + kb);
          #pragma unroll
          for (int i=0;i<16;i++){
            s8v a0=ap0[q+4*i], a1=ap1[q+4*i];
            aC0=MFMA(a0,BL.c[i],aC0); aC1=MFMA(a1,BL.c[i],aC1);
            aH0=MFMA(a0,BL.h[i],aH0); aH1=MFMA(a1,BL.h[i],aH1);
          }
        }
        #pragma unroll
        for (int i=0;i<4;i++){
          red[((wave*4+0)*32 + q*4+i)*16 + r]    = aC0[i];
          red[((wave*4+0)*32 + 16+q*4+i)*16 + r] = aC1[i];
          red[((wave*4+1)*32 + q*4+i)*16 + r]    = aH0[i];
          red[((wave*4+1)*32 + 16+q*4+i)*16 + r] = aH1[i];
        }
        __syncthreads();
        int row = tid>>3, col = (tid&7)*2;
        float cs0=0,cs1=0,hs0=0,hs1=0;
        #pragma unroll
        for (int w2=0; w2<4; w2++){
          cs0 += red[((w2*4+0)*32+row)*16+col];
          cs1 += red[((w2*4+0)*32+row)*16+col+1];
          hs0 += red[((w2*4+1)*32+row)*16+col];
          hs1 += red[((w2*4+1)*32+row)*16+col+1];
        }
        const float* hfb = t ? h_f : h0f;
        size_t off = (size_t)row*NHID + j0 + col;
        float hp0 = hfb[off], hp1 = hfb[off+1];
        float v0 = hp0 + sigf(cs0)*(tanhf(hs0)-hp0);
        float v1 = hp1 + sigf(cs1)*(tanhf(hs1)-hp1);
        __hip_atomic_store(&st_f[off],   v0, __ATOMIC_RELAXED, __HIP_MEMORY_SCOPE_AGENT);
        __hip_atomic_store(&st_f[off+1], v1, __ATOMIC_RELAXED, __HIP_MEMORY_SCOPE_AGENT);
        unsigned pk = (unsigned)f2bf(v0) | ((unsigned)f2bf(v1)<<16);
        __hip_atomic_store((unsigned*)(st_bf + off), pk,
                           __ATOMIC_RELAXED, __HIP_MEMORY_SCOPE_AGENT);
        wg_signal(&cnt[0]);
      }
      // ---- L3: e3 (identity, pred s1, out s4) ----
      do_edge_reg(B3, st_f, st_bf, red, cnt, 1, 4, 3, j0, tgt, wave, q, r, tid);
    }
  } else if (grp == 1) {
    B8 B0; load_b8(Wt, 2, j0, r, wave*256, q, B0);   // e0: sigmoid, s0->s1
    B8 B4; load_b8(Wt, 6, j0, r, wave*256, q, B4);   // e4: tanh,    s2->s5
    for (int t = 0; t < TT; ++t) {
      unsigned tgt = 64u*(t+1);
      do_edge_reg(B0, st_f, st_bf, red, cnt, 0, 1, 0, j0, tgt, wave, q, r, tid);
      do_edge_reg(B4, st_f, st_bf, red, cnt, 2, 5, 2, j0, tgt, wave, q, r, tid);
    }
  } else if (grp == 2) {
    B8 B1; load_b8(Wt, 3, j0, r, wave*256, q, B1);   // e1: relu, s1->s2
    B8 B6; load_b8(Wt, 8, j0, r, wave*256, q, B6);   // e6: tanh, s3->s7
    for (int t = 0; t < TT; ++t) {
      unsigned tgt = 64u*(t+1);
      do_edge_reg(B1, st_f, st_bf, red, cnt, 1, 2, 1, j0, tgt, wave, q, r, tid);
      do_edge_reg(B6, st_f, st_bf, red, cnt, 3, 7, 2, j0, tgt, wave, q, r, tid);
    }
  } else {
    B8 B2; load_b8(Wt, 4, j0, r, wave*256, q, B2);   // e2: relu, s1->s3
    B8 B5; load_b8(Wt, 7, j0, r, wave*256, q, B5);   // e5: sigmoid, s5->s6
    B8 B7; load_b8(Wt, 9, j0, r, wave*256, q, B7);   // e7: relu,    s5->s8
    for (int t = 0; t < TT; ++t) {
      unsigned tgt = 64u*(t+1);
      // ---- L3: e2 (relu, pred s1, out s3) ----
      do_edge_reg(B2, st_f, st_bf, red, cnt, 1, 3, 1, j0, tgt, wave, q, r, tid);
      // ---- L5: fused e5 (sigmoid) + e7 (relu), pred s5; compute mean h ----
      wg_wait(&cnt[4], tgt);
      wg_wait(&cnt[5], tgt);
      wg_wait(&cnt[7], tgt);
      {
        const unsigned short* spb = st_bf + (size_t)5*BN;
        int kb = wave*256;
        const s8v* ap0 = (const s8v*)(spb + (size_t)r*NHID + kb);
        const s8v* ap1 = (const s8v*)(spb + (size_t)(16+r)*NHID + kb);
        f4v zz = {0.f,0.f,0.f,0.f};
        f4v c50=zz,c51=zz,h50=zz,h51=zz,c70=zz,c71=zz,h70=zz,h71=zz;
        #pragma unroll
        for (int i=0;i<8;i++){
          s8v a0=ap0[q+4*i], a1=ap1[q+4*i];
          c50=MFMA(a0,B5.c[i],c50); c51=MFMA(a1,B5.c[i],c51);
          h50=MFMA(a0,B5.h[i],h50); h51=MFMA(a1,B5.h[i],h51);
          c70=MFMA(a0,B7.c[i],c70); c71=MFMA(a1,B7.c[i],c71);
          h70=MFMA(a0,B7.h[i],h70); h71=MFMA(a1,B7.h[i],h71);
        }
        #pragma unroll
        for (int i=0;i<4;i++){
          red[((wave*4+0)*32 + q*4+i)*16 + r]    = c50[i];
          red[((wave*4+0)*32 + 16+q*4+i)*16 + r] = c51[i];
          red[((wave*4+1)*32 + q*4+i)*16 + r]    = h50[i];
          red[((wave*4+1)*32 + 16+q*4+i)*16 + r] = h51[i];
          red[((wave*4+2)*32 + q*4+i)*16 + r]    = c70[i];
          red[((wave*4+2)*32 + 16+q*4+i)*16 + r] = c71[i];
          red[((wave*4+3)*32 + q*4+i)*16 + r]    = h70[i];
          red[((wave*4+3)*32 + 16+q*4+i)*16 + r] = h71[i];
        }
        __syncthreads();
        int row = tid>>3, col = (tid&7)*2;
        float a5c[2]={0,0}, a5h[2]={0,0}, a7c[2]={0,0}, a7h[2]={0,0};
        #pragma unroll
        for (int w2=0; w2<4; w2++){
          #pragma unroll
          for (int u=0; u<2; u++){
            a5c[u] += red[((w2*4+0)*32+row)*16+col+u];
            a5h[u] += red[((w2*4+1)*32+row)*16+col+u];
            a7c[u] += red[((w2*4+2)*32+row)*16+col+u];
            a7h[u] += red[((w2*4+3)*32+row)*16+col+u];
          }
        }
        size_t off = (size_t)row*NHID + j0 + col;
        float hv[2];
        #pragma unroll
        for (int u=0; u<2; u++){
          float s5j = st_f[(size_t)5*BN + off + u];
          float s6 = s5j + sigf(a5c[u])*(sigf(a5h[u]) - s5j);
          float s8 = s5j + sigf(a7c[u])*(fmaxf(a7h[u],0.f) - s5j);
          float sum = st_f[(size_t)1*BN+off+u] + st_f[(size_t)2*BN+off+u]
                    + st_f[(size_t)3*BN+off+u] + st_f[(size_t)4*BN+off+u]
                    + s5j + s6 + st_f[(size_t)7*BN+off+u] + s8;
          hv[u] = 0.125f * sum;
          __hip_atomic_store(&h_f[off+u], hv[u], __ATOMIC_RELAXED, __HIP_MEMORY_SCOPE_AGENT);
        }
        unsigned pk = (unsigned)f2bf(hv[0]) | ((unsigned)f2bf(hv[1])<<16);
        __hip_atomic_store((unsigned*)(h_bf + off), pk,
                           __ATOMIC_RELAXED, __HIP_MEMORY_SCOPE_AGENT);
        *(unsigned*)(hid_bf + (size_t)t*BN + off) = pk;   // consumed post-kernel
        wg_signal(&cnt[8]);
      }
    }
  }
}

// ---------------- decoder ----------------

__global__ __launch_bounds__(256) void k_decoder(
    const unsigned short* __restrict__ Hb, const unsigned short* __restrict__ Wb,
    float* __restrict__ out)
{
  int wave = threadIdx.x >> 6, lane = threadIdx.x & 63;
  int q = lane >> 4, r = lane & 15;
  int bm = blockIdx.y*64 + (wave>>1)*32;
  int bn = blockIdx.x*64 + (wave&1)*32;
  f4v z = {0.f,0.f,0.f,0.f};
  f4v acc00=z, acc01=z, acc10=z, acc11=z;
  const s8v* a0p = (const s8v*)(Hb + (size_t)(bm + r)*NHID);
  const s8v* a1p = (const s8v*)(Hb + (size_t)(bm + 16 + r)*NHID);
  int n0 = bn + r, n1 = bn + 16 + r;
  const s8v* b0p = (const s8v*)(Wb + (size_t)(n0 < NTOK ? n0 : 0)*NHID);
  const s8v* b1p = (const s8v*)(Wb + (size_t)(n1 < NTOK ? n1 : 0)*NHID);
  #pragma unroll 4
  for (int v = q; v < 128; v += 4) {
    s8v a0 = a0p[v], a1 = a1p[v], b0 = b0p[v], b1 = b1p[v];
    acc00 = MFMA(a0, b0, acc00); acc10 = MFMA(a1, b0, acc10);
    acc01 = MFMA(a0, b1, acc01); acc11 = MFMA(a1, b1, acc11);
  }
  #pragma unroll
  for (int ni=0; ni<2; ni++){
    int col = bn + ni*16 + r;
    if (col >= NTOK) continue;
    #pragma unroll
    for (int mi=0; mi<2; mi++){
      f4v a = (mi==0) ? (ni==0 ? acc00 : acc01) : (ni==0 ? acc10 : acc11);
      #pragma unroll
      for (int t4=0; t4<4; t4++){
        int row = bm + mi*16 + q*4 + t4;
        out[(size_t)row*NTOK + col] = a[t4];
      }
    }
  }
}

__global__ __launch_bounds__(256) void k_logsoftmax(
    float* __restrict__ logits, const float* __restrict__ bias)
{
  size_t row = blockIdx.x;
  float* p = logits + row * NTOK;
  float v[40];
  float mx = -1e30f;
  #pragma unroll
  for (int i=0;i<40;i++){
    int c = threadIdx.x + (i<<8);
    float x = (c < NTOK) ? (p[c] + bias[c]) : -1e30f;
    v[i] = x; mx = fmaxf(mx, x);
  }
  #pragma unroll
  for (int off=32; off>0; off>>=1) mx = fmaxf(mx, __shfl_down(mx, off));
  __shared__ float red[4], red2[4];
  int wv = threadIdx.x>>6, ln = threadIdx.x&63;
  if (ln==0) red[wv] = mx;
  __syncthreads();
  mx = fmaxf(fmaxf(red[0],red[1]), fmaxf(red[2],red[3]));
  float s = 0.f;
  #pragma unroll
  for (int i=0;i<40;i++) s += __expf(v[i] - mx);
  #pragma unroll
  for (int off=32; off>0; off>>=1) s += __shfl_down(s, off);
  if (ln==0) red2[wv] = s;
  __syncthreads();
  s = red2[0]+red2[1]+red2[2]+red2[3];
  float lse = mx + __logf(s);
  #pragma unroll
  for (int i=0;i<40;i++){
    int c = threadIdx.x + (i<<8);
    if (c < NTOK) p[c] = v[i] - lse;
  }
}

__global__ void k_copy(const float* __restrict__ src, float* __restrict__ dst, int n){
  int i = blockIdx.x*blockDim.x + threadIdx.x;
  if (i < n) dst[i] = src[i];
}

// ---------------- launch ----------------

extern "C" void kernel_launch(void* const* d_in, const int* in_sizes, int n_in,
                              void* d_out, int out_size, void* d_ws, size_t ws_size,
                              hipStream_t stream) {
  const int*   tok  = (const int*)d_in[0];
  const float* h0   = (const float*)d_in[1];
  const float* encw = (const float*)d_in[2];
  const float* W0   = (const float*)d_in[3];
  const float* Ws   = (const float*)d_in[4];
  const float* decb = (const float*)d_in[5];
  float* out = (float*)d_out;

  char* w = (char*)d_ws;
  unsigned short* Wt      = (unsigned short*)w; w += (size_t)10*WMAT*2;
  unsigned short* encw_bf = (unsigned short*)w; w += (size_t)NTOK*NHID*2;
  unsigned short* h0_bf   = (unsigned short*)w; w += (size_t)BN*2;
  unsigned short* hid_bf  = (unsigned short*)w; w += (size_t)TT*BN*2;
  float*          st_f    = (float*)w;          w += (size_t)9*BN*4;
  unsigned short* st_bf   = (unsigned short*)w; w += (size_t)9*BN*2;
  float*          h_f     = (float*)w;          w += (size_t)BN*4;
  unsigned short* h_bf    = (unsigned short*)w; w += (size_t)BN*2;
  unsigned*       cnt     = (unsigned*)w;       w += 64;

  k_zero<<<1, 64, 0, stream>>>(cnt);
  k_transpose_cvt<<<dim3(64,32,10), 256, 0, stream>>>(W0, Ws, Wt);
  k_cvt<<<4096, 256, 0, stream>>>(encw, encw_bf, NTOK*NHID);
  k_cvt<<<128, 256, 0, stream>>>(h0, h0_bf, BN);

  k_recur<<<256, 256, 0, stream>>>(tok, h0, encw_bf, Wt, h0_bf,
                                   st_f, st_bf, h_f, h_bf, hid_bf, cnt);

  k_decoder<<<dim3(157,64), 256, 0, stream>>>(hid_bf, encw_bf, out);
  k_logsoftmax<<<TT*BB, 256, 0, stream>>>(out, decb);
  k_copy<<<128, 256, 0, stream>>>(h_f, out + (size_t)TT*BB*NTOK, BN);
}

// Round 3
// 5359.818 us; speedup vs baseline: 1.7962x; 1.4686x over previous
//
#include <hip/hip_runtime.h>
#include <cmath>

#define NHID 1024
#define NTOK 10000
#define TT 128
#define BB 32
#define BN (BB*NHID)            // elems per (B,NHID) state
#define WMAT (2048*1024)        // elems per transposed weight matrix
#define FSTRIDE 16              // flag padding: 16 dwords = 64B per flag

typedef __attribute__((ext_vector_type(8))) short s8v;   // 8 x bf16 raw
typedef __attribute__((ext_vector_type(4))) float f4v;   // MFMA accumulator

#define MFMA(a,b,c) __builtin_amdgcn_mfma_f32_16x16x32_bf16(a,b,c,0,0,0)

__device__ __forceinline__ float sigf(float x){ return 1.f/(1.f+__expf(-x)); }
__device__ __forceinline__ float actf(int a, float h){
  switch(a){ case 0: return sigf(h); case 1: return fmaxf(h,0.f);
             case 2: return tanhf(h); default: return h; }
}
__device__ __forceinline__ unsigned short f2bf(float x){
  union { float f; unsigned u; } v; v.f = x;
  unsigned r = v.u + 0x7fffu + ((v.u >> 16) & 1u);
  return (unsigned short)(r >> 16);
}

// coherent 16B state load as two 64-bit relaxed agent atomic loads
// (compiler-visible -> spill-safe; agent atomic loads read the L3 coherence
// point, proven by the Round-1 poll loop observing remote updates)
__device__ __forceinline__ s8v ld_a16(const unsigned short* p){
  union { unsigned long long u[2]; s8v v; } x;
  x.u[0] = __hip_atomic_load((const unsigned long long*)p,
                             __ATOMIC_RELAXED, __HIP_MEMORY_SCOPE_AGENT);
  x.u[1] = __hip_atomic_load(((const unsigned long long*)p)+1,
                             __ATOMIC_RELAXED, __HIP_MEMORY_SCOPE_AGENT);
  return x.v;
}
__device__ __forceinline__ void ld_f2(const float* p, float& x0, float& x1){
  unsigned long long u = __hip_atomic_load((const unsigned long long*)p,
                         __ATOMIC_RELAXED, __HIP_MEMORY_SCOPE_AGENT);
  union { unsigned long long u; float f[2]; } v; v.u = u;
  x0 = v.f[0]; x1 = v.f[1];
}

// ---------------- prep kernels ----------------

__global__ __launch_bounds__(256) void k_transpose_cvt(
    const float* __restrict__ W0, const float* __restrict__ Ws,
    unsigned short* __restrict__ dstAll)
{
  int z = blockIdx.z;
  const float* src = (z==0) ? W0 : (z==1) ? (W0 + (size_t)1024*2048)
                                          : (Ws + (size_t)(z-2)*1024*2048);
  unsigned short* dst = dstAll + (size_t)z*WMAT;
  __shared__ float tile[32][33];
  int n0 = blockIdx.x*32;
  int k0 = blockIdx.y*32;
  int tx = threadIdx.x & 31, ty = threadIdx.x >> 5;
  #pragma unroll
  for (int i=0;i<4;i++){
    int k = k0 + ty + i*8;
    tile[ty + i*8][tx] = src[(size_t)k*2048 + n0 + tx];
  }
  __syncthreads();
  #pragma unroll
  for (int i=0;i<4;i++){
    int n = n0 + ty + i*8;
    dst[(size_t)n*1024 + k0 + tx] = f2bf(tile[tx][ty + i*8]);
  }
}

__global__ void k_cvt(const float* __restrict__ src, unsigned short* __restrict__ dst, int n){
  int i = blockIdx.x*blockDim.x + threadIdx.x;
  int stride = gridDim.x*blockDim.x;
  for (; i < n; i += stride) dst[i] = f2bf(src[i]);
}

__global__ void k_zero(unsigned* __restrict__ p, int n){
  int i = blockIdx.x*blockDim.x + threadIdx.x;
  if (i < n) p[i] = 0u;
}

// ---------------- persistent recurrence kernel ----------------
// grid = 256 WGs x 256 threads (4 waves), 1 per CU, all co-resident.
// Sync design:
//  * per-(state,tile) flags, padded to 64B: producer does ONE release store
//    (wbl2 flushes its XCD L2 -> data at L3 before flag) instead of the old
//    64-way serialized fetch_add on one cache line.
//  * consumers poll relaxed (agent atomic loads read L3) and read state data
//    via relaxed agent atomic loads -> NO acquire / buffer_inv anywhere, so
//    read-only data (weights/embeddings/tokens) stays cached across steps.

__device__ __forceinline__ void wait1(const unsigned* F, int s, unsigned tgt){
  if (threadIdx.x < 64){
    const unsigned* f = F + (size_t)((s<<6) + threadIdx.x)*FSTRIDE;
    while (__hip_atomic_load(f, __ATOMIC_RELAXED, __HIP_MEMORY_SCOPE_AGENT) < tgt)
      __builtin_amdgcn_s_sleep(1);
  }
  __syncthreads();
}
__device__ __forceinline__ void wait3(const unsigned* F, int s0, int s1, int s2, unsigned tgt){
  if (threadIdx.x < 64){
    const unsigned* f0 = F + (size_t)((s0<<6) + threadIdx.x)*FSTRIDE;
    const unsigned* f1 = F + (size_t)((s1<<6) + threadIdx.x)*FSTRIDE;
    const unsigned* f2 = F + (size_t)((s2<<6) + threadIdx.x)*FSTRIDE;
    for (;;){
      unsigned a = __hip_atomic_load(f0, __ATOMIC_RELAXED, __HIP_MEMORY_SCOPE_AGENT);
      unsigned b = __hip_atomic_load(f1, __ATOMIC_RELAXED, __HIP_MEMORY_SCOPE_AGENT);
      unsigned c = __hip_atomic_load(f2, __ATOMIC_RELAXED, __HIP_MEMORY_SCOPE_AGENT);
      if (a >= tgt && b >= tgt && c >= tgt) break;
      __builtin_amdgcn_s_sleep(1);
    }
  }
  __syncthreads();
}
__device__ __forceinline__ void signal(unsigned* F, int s, int tile, unsigned val){
  __syncthreads();   // per-wave vmcnt drain: all waves' data stores complete
  if (threadIdx.x == 0)
    __hip_atomic_store(F + (size_t)((s<<6)+tile)*FSTRIDE, val,
                       __ATOMIC_RELEASE, __HIP_MEMORY_SCOPE_AGENT);
}

struct B8  { s8v c[8];  s8v h[8];  };   //  64 VGPRs: one edge task, K=256/wave
struct B16 { s8v c[16]; s8v h[16]; };   // 128 VGPRs: L1 (K=512/wave)

__device__ __forceinline__ void load_b8(const unsigned short* __restrict__ Wt,
                                        int z, int j0, int r, int kb, int q, B8& B){
  const unsigned short* wz = Wt + (size_t)z*WMAT;
  const s8v* bc = (const s8v*)(wz + (size_t)(j0+r)*1024 + kb);
  const s8v* bh = (const s8v*)(wz + (size_t)(1024+j0+r)*1024 + kb);
  #pragma unroll
  for (int i=0;i<8;i++){ B.c[i]=bc[q+4*i]; B.h[i]=bh[q+4*i]; }
}

// one edge task with weights in registers: 16 paired cols (tile j0),
// K=1024 split 4 ways over waves
__device__ __forceinline__ void do_edge_reg(
    const B8& B, float* __restrict__ st_f,
    unsigned short* __restrict__ st_bf, float* __restrict__ red,
    unsigned* __restrict__ F, int pred, int outs, int act,
    int j0, int tile, unsigned tgt, int wave, int q, int r, int tid)
{
  wait1(F, pred, tgt);
  int row = tid>>3, col = (tid&7)*2;
  size_t off = (size_t)row*NHID + j0 + col;
  float sp0, sp1;                                  // epilogue operand: prefetch
  ld_f2(st_f + (size_t)pred*BN + off, sp0, sp1);   // early, hides under MFMAs
  const unsigned short* spb = st_bf + (size_t)pred*BN;
  int kb = wave*256;
  const unsigned short* p0 = spb + (size_t)r*NHID + kb;
  const unsigned short* p1 = spb + (size_t)(16+r)*NHID + kb;
  s8v a0[8], a1[8];
  #pragma unroll
  for (int i=0;i<8;i++){
    a0[i] = ld_a16(p0 + (q+4*i)*8);
    a1[i] = ld_a16(p1 + (q+4*i)*8);
  }
  f4v zz = {0.f,0.f,0.f,0.f};
  f4v aC0=zz,aC1=zz,aH0=zz,aH1=zz;
  #pragma unroll
  for (int i=0;i<8;i++){
    aC0=MFMA(a0[i],B.c[i],aC0); aC1=MFMA(a1[i],B.c[i],aC1);
    aH0=MFMA(a0[i],B.h[i],aH0); aH1=MFMA(a1[i],B.h[i],aH1);
  }
  #pragma unroll
  for (int i=0;i<4;i++){
    red[((wave*4+0)*32 + q*4+i)*16 + r]    = aC0[i];
    red[((wave*4+0)*32 + 16+q*4+i)*16 + r] = aC1[i];
    red[((wave*4+1)*32 + q*4+i)*16 + r]    = aH0[i];
    red[((wave*4+1)*32 + 16+q*4+i)*16 + r] = aH1[i];
  }
  __syncthreads();
  float cs0=0,cs1=0,hs0=0,hs1=0;
  #pragma unroll
  for (int w2=0; w2<4; w2++){
    cs0 += red[((w2*4+0)*32+row)*16+col];
    cs1 += red[((w2*4+0)*32+row)*16+col+1];
    hs0 += red[((w2*4+1)*32+row)*16+col];
    hs1 += red[((w2*4+1)*32+row)*16+col+1];
  }
  float v0 = sp0 + sigf(cs0)*(actf(act,hs0) - sp0);
  float v1 = sp1 + sigf(cs1)*(actf(act,hs1) - sp1);
  __hip_atomic_store(&st_f[(size_t)outs*BN+off],   v0, __ATOMIC_RELAXED, __HIP_MEMORY_SCOPE_AGENT);
  __hip_atomic_store(&st_f[(size_t)outs*BN+off+1], v1, __ATOMIC_RELAXED, __HIP_MEMORY_SCOPE_AGENT);
  unsigned pk = (unsigned)f2bf(v0) | ((unsigned)f2bf(v1)<<16);
  __hip_atomic_store((unsigned*)(st_bf + (size_t)outs*BN + off), pk,
                     __ATOMIC_RELAXED, __HIP_MEMORY_SCOPE_AGENT);
  signal(F, outs, tile, tgt);
}

__global__ __launch_bounds__(256, 1) void k_recur(
    const int* __restrict__ tok, const float* __restrict__ h0f,
    const unsigned short* __restrict__ encb,
    const unsigned short* __restrict__ Wt,
    const unsigned short* __restrict__ h0b,
    float* __restrict__ st_f, unsigned short* __restrict__ st_bf,
    float* __restrict__ h_f, unsigned short* __restrict__ h_bf,
    unsigned short* __restrict__ hid_bf, unsigned* __restrict__ F)
{
  __shared__ float red[4*4*32*16];   // 32 KB: [wave][ch up to 4][row 32][col 16]
  int wg = blockIdx.x, grp = wg >> 6, tile = wg & 63;
  int tid = threadIdx.x, wave = tid>>6, lane = tid&63, q = lane>>4, r = lane&15;
  int j0 = tile * 16;

  if (grp == 0) {
    // ---- weights resident in VGPRs for the whole kernel ----
    B16 BL;   // L1 init matmul; wave-specific K-chunk of the 2048-deep W0
    {
      const unsigned short* wz = Wt + (size_t)(wave>>1)*WMAT;
      int kloc = (wave & 1) * 512;
      const s8v* bc = (const s8v*)(wz + (size_t)(j0+r)*1024 + kloc);
      const s8v* bh = (const s8v*)(wz + (size_t)(1024+j0+r)*1024 + kloc);
      #pragma unroll
      for (int i=0;i<16;i++){ BL.c[i]=bc[q+4*i]; BL.h[i]=bh[q+4*i]; }
    }
    B8 B3; load_b8(Wt, 5, j0, r, wave*256, q, B3);   // e3: identity, s1->s4

    for (int t = 0; t < TT; ++t) {
      unsigned tgt = t+1;
      // ---- L1: init (K=2048: waves 0-1 take x half, 2-3 take h half) ----
      // issue static embedding A-operand loads BEFORE waiting on h(t-1):
      // plain cached loads (read-only data), latency hides under the poll
      s8v xa0[16], xa1[16];
      if (wave < 2){
        int kb = wave * 512;
        const s8v* e0p = (const s8v*)(encb + (size_t)tok[t*BB + r]*NHID + kb);
        const s8v* e1p = (const s8v*)(encb + (size_t)tok[t*BB + 16 + r]*NHID + kb);
        #pragma unroll
        for (int i=0;i<16;i++){ xa0[i]=e0p[q+4*i]; xa1[i]=e1p[q+4*i]; }
      }
      if (t) wait1(F, 8, t);
      int row = tid>>3, col = (tid&7)*2;
      size_t off = (size_t)row*NHID + j0 + col;
      const float* hfb = t ? h_f : h0f;
      float hp0, hp1; ld_f2(hfb + off, hp0, hp1);
      f4v zz = {0.f,0.f,0.f,0.f};
      f4v aC0=zz,aC1=zz,aH0=zz,aH1=zz;
      if (wave < 2) {
        #pragma unroll
        for (int i=0;i<16;i++){
          s8v a0=xa0[i], a1=xa1[i];
          aC0=MFMA(a0,BL.c[i],aC0); aC1=MFMA(a1,BL.c[i],aC1);
          aH0=MFMA(a0,BL.h[i],aH0); aH1=MFMA(a1,BL.h[i],aH1);
        }
      } else {
        const unsigned short* hb = t ? h_bf : h0b;
        int kb = (wave-2)*512;
        const unsigned short* g0 = hb + (size_t)r*NHID + kb;
        const unsigned short* g1 = hb + (size_t)(16+r)*NHID + kb;
        s8v ha0[16], ha1[16];
        #pragma unroll
        for (int i=0;i<16;i++){ ha0[i]=ld_a16(g0+(q+4*i)*8); ha1[i]=ld_a16(g1+(q+4*i)*8); }
        #pragma unroll
        for (int i=0;i<16;i++){
          aC0=MFMA(ha0[i],BL.c[i],aC0); aC1=MFMA(ha1[i],BL.c[i],aC1);
          aH0=MFMA(ha0[i],BL.h[i],aH0); aH1=MFMA(ha1[i],BL.h[i],aH1);
        }
      }
      #pragma unroll
      for (int i=0;i<4;i++){
        red[((wave*4+0)*32 + q*4+i)*16 + r]    = aC0[i];
        red[((wave*4+0)*32 + 16+q*4+i)*16 + r] = aC1[i];
        red[((wave*4+1)*32 + q*4+i)*16 + r]    = aH0[i];
        red[((wave*4+1)*32 + 16+q*4+i)*16 + r] = aH1[i];
      }
      __syncthreads();
      float cs0=0,cs1=0,hs0=0,hs1=0;
      #pragma unroll
      for (int w2=0; w2<4; w2++){
        cs0 += red[((w2*4+0)*32+row)*16+col];
        cs1 += red[((w2*4+0)*32+row)*16+col+1];
        hs0 += red[((w2*4+1)*32+row)*16+col];
        hs1 += red[((w2*4+1)*32+row)*16+col+1];
      }
      float v0 = hp0 + sigf(cs0)*(tanhf(hs0)-hp0);
      float v1 = hp1 + sigf(cs1)*(tanhf(hs1)-hp1);
      __hip_atomic_store(&st_f[off],   v0, __ATOMIC_RELAXED, __HIP_MEMORY_SCOPE_AGENT);
      __hip_atomic_store(&st_f[off+1], v1, __ATOMIC_RELAXED, __HIP_MEMORY_SCOPE_AGENT);
      unsigned pk = (unsigned)f2bf(v0) | ((unsigned)f2bf(v1)<<16);
      __hip_atomic_store((unsigned*)(st_bf + off), pk,
                         __ATOMIC_RELAXED, __HIP_MEMORY_SCOPE_AGENT);
      signal(F, 0, tile, tgt);
      // ---- e3 (identity, pred s1, out s4) ----
      do_edge_reg(B3, st_f, st_bf, red, F, 1, 4, 3, j0, tile, tgt, wave, q, r, tid);
    }
  } else if (grp == 1) {
    B8 B0; load_b8(Wt, 2, j0, r, wave*256, q, B0);   // e0: sigmoid, s0->s1
    B8 B4; load_b8(Wt, 6, j0, r, wave*256, q, B4);   // e4: tanh,    s2->s5
    for (int t = 0; t < TT; ++t) {
      unsigned tgt = t+1;
      do_edge_reg(B0, st_f, st_bf, red, F, 0, 1, 0, j0, tile, tgt, wave, q, r, tid);
      do_edge_reg(B4, st_f, st_bf, red, F, 2, 5, 2, j0, tile, tgt, wave, q, r, tid);
    }
  } else if (grp == 2) {
    B8 B1; load_b8(Wt, 3, j0, r, wave*256, q, B1);   // e1: relu, s1->s2
    B8 B6; load_b8(Wt, 8, j0, r, wave*256, q, B6);   // e6: tanh, s3->s7
    for (int t = 0; t < TT; ++t) {
      unsigned tgt = t+1;
      do_edge_reg(B1, st_f, st_bf, red, F, 1, 2, 1, j0, tile, tgt, wave, q, r, tid);
      do_edge_reg(B6, st_f, st_bf, red, F, 3, 7, 2, j0, tile, tgt, wave, q, r, tid);
    }
  } else {
    B8 B2; load_b8(Wt, 4, j0, r, wave*256, q, B2);   // e2: relu, s1->s3
    B8 B5; load_b8(Wt, 7, j0, r, wave*256, q, B5);   // e5: sigmoid, s5->s6
    B8 B7; load_b8(Wt, 9, j0, r, wave*256, q, B7);   // e7: relu,    s5->s8
    for (int t = 0; t < TT; ++t) {
      unsigned tgt = t+1;
      // ---- e2 (relu, pred s1, out s3) ----
      do_edge_reg(B2, st_f, st_bf, red, F, 1, 3, 1, j0, tile, tgt, wave, q, r, tid);
      // ---- fused e5 (sigmoid) + e7 (relu), pred s5; compute mean h ----
      // waiting {4,5,7} transitively covers s1,s2,s3 completion as well
      wait3(F, 4, 5, 7, tgt);
      {
        int row = tid>>3, col = (tid&7)*2;
        size_t off = (size_t)row*NHID + j0 + col;
        float s1a,s1b,s2a,s2b,s3a,s3b,s4a,s4b,s5a,s5b,s7a,s7b;
        ld_f2(st_f + (size_t)1*BN + off, s1a, s1b);
        ld_f2(st_f + (size_t)2*BN + off, s2a, s2b);
        ld_f2(st_f + (size_t)3*BN + off, s3a, s3b);
        ld_f2(st_f + (size_t)4*BN + off, s4a, s4b);
        ld_f2(st_f + (size_t)5*BN + off, s5a, s5b);
        ld_f2(st_f + (size_t)7*BN + off, s7a, s7b);
        const unsigned short* spb = st_bf + (size_t)5*BN;
        int kb = wave*256;
        const unsigned short* p0 = spb + (size_t)r*NHID + kb;
        const unsigned short* p1 = spb + (size_t)(16+r)*NHID + kb;
        s8v a0[8], a1[8];
        #pragma unroll
        for (int i=0;i<8;i++){ a0[i]=ld_a16(p0+(q+4*i)*8); a1[i]=ld_a16(p1+(q+4*i)*8); }
        f4v zz = {0.f,0.f,0.f,0.f};
        f4v c50=zz,c51=zz,h50=zz,h51=zz,c70=zz,c71=zz,h70=zz,h71=zz;
        #pragma unroll
        for (int i=0;i<8;i++){
          c50=MFMA(a0[i],B5.c[i],c50); c51=MFMA(a1[i],B5.c[i],c51);
          h50=MFMA(a0[i],B5.h[i],h50); h51=MFMA(a1[i],B5.h[i],h51);
          c70=MFMA(a0[i],B7.c[i],c70); c71=MFMA(a1[i],B7.c[i],c71);
          h70=MFMA(a0[i],B7.h[i],h70); h71=MFMA(a1[i],B7.h[i],h71);
        }
        #pragma unroll
        for (int i=0;i<4;i++){
          red[((wave*4+0)*32 + q*4+i)*16 + r]    = c50[i];
          red[((wave*4+0)*32 + 16+q*4+i)*16 + r] = c51[i];
          red[((wave*4+1)*32 + q*4+i)*16 + r]    = h50[i];
          red[((wave*4+1)*32 + 16+q*4+i)*16 + r] = h51[i];
          red[((wave*4+2)*32 + q*4+i)*16 + r]    = c70[i];
          red[((wave*4+2)*32 + 16+q*4+i)*16 + r] = c71[i];
          red[((wave*4+3)*32 + q*4+i)*16 + r]    = h70[i];
          red[((wave*4+3)*32 + 16+q*4+i)*16 + r] = h71[i];
        }
        __syncthreads();
        float a5c[2]={0,0}, a5h[2]={0,0}, a7c[2]={0,0}, a7h[2]={0,0};
        #pragma unroll
        for (int w2=0; w2<4; w2++){
          #pragma unroll
          for (int u=0; u<2; u++){
            a5c[u] += red[((w2*4+0)*32+row)*16+col+u];
            a5h[u] += red[((w2*4+1)*32+row)*16+col+u];
            a7c[u] += red[((w2*4+2)*32+row)*16+col+u];
            a7h[u] += red[((w2*4+3)*32+row)*16+col+u];
          }
        }
        float s5v[2] = {s5a, s5b};
        float o1[2] = {s1a, s1b}, o2[2] = {s2a, s2b}, o3[2] = {s3a, s3b};
        float o4[2] = {s4a, s4b}, o7[2] = {s7a, s7b};
        float hv[2];
        #pragma unroll
        for (int u=0; u<2; u++){
          float s5j = s5v[u];
          float s6 = s5j + sigf(a5c[u])*(sigf(a5h[u]) - s5j);
          float s8 = s5j + sigf(a7c[u])*(fmaxf(a7h[u],0.f) - s5j);
          float sum = o1[u] + o2[u] + o3[u] + o4[u]
                    + s5j + s6 + o7[u] + s8;
          hv[u] = 0.125f * sum;
          __hip_atomic_store(&h_f[off+u], hv[u], __ATOMIC_RELAXED, __HIP_MEMORY_SCOPE_AGENT);
        }
        unsigned pk = (unsigned)f2bf(hv[0]) | ((unsigned)f2bf(hv[1])<<16);
        __hip_atomic_store((unsigned*)(h_bf + off), pk,
                           __ATOMIC_RELAXED, __HIP_MEMORY_SCOPE_AGENT);
        *(unsigned*)(hid_bf + (size_t)t*BN + off) = pk;   // consumed post-kernel
        signal(F, 8, tile, tgt);
      }
    }
  }
}

// ---------------- decoder ----------------

__global__ __launch_bounds__(256) void k_decoder(
    const unsigned short* __restrict__ Hb, const unsigned short* __restrict__ Wb,
    float* __restrict__ out)
{
  int wave = threadIdx.x >> 6, lane = threadIdx.x & 63;
  int q = lane >> 4, r = lane & 15;
  int bm = blockIdx.y*64 + (wave>>1)*32;
  int bn = blockIdx.x*64 + (wave&1)*32;
  f4v z = {0.f,0.f,0.f,0.f};
  f4v acc00=z, acc01=z, acc10=z, acc11=z;
  const s8v* a0p = (const s8v*)(Hb + (size_t)(bm + r)*NHID);
  const s8v* a1p = (const s8v*)(Hb + (size_t)(bm + 16 + r)*NHID);
  int n0 = bn + r, n1 = bn + 16 + r;
  const s8v* b0p = (const s8v*)(Wb + (size_t)(n0 < NTOK ? n0 : 0)*NHID);
  const s8v* b1p = (const s8v*)(Wb + (size_t)(n1 < NTOK ? n1 : 0)*NHID);
  #pragma unroll 4
  for (int v = q; v < 128; v += 4) {
    s8v a0 = a0p[v], a1 = a1p[v], b0 = b0p[v], b1 = b1p[v];
    acc00 = MFMA(a0, b0, acc00); acc10 = MFMA(a1, b0, acc10);
    acc01 = MFMA(a0, b1, acc01); acc11 = MFMA(a1, b1, acc11);
  }
  #pragma unroll
  for (int ni=0; ni<2; ni++){
    int col = bn + ni*16 + r;
    if (col >= NTOK) continue;
    #pragma unroll
    for (int mi=0; mi<2; mi++){
      f4v a = (mi==0) ? (ni==0 ? acc00 : acc01) : (ni==0 ? acc10 : acc11);
      #pragma unroll
      for (int t4=0; t4<4; t4++){
        int row = bm + mi*16 + q*4 + t4;
        out[(size_t)row*NTOK + col] = a[t4];
      }
    }
  }
}

__global__ __launch_bounds__(256) void k_logsoftmax(
    float* __restrict__ logits, const float* __restrict__ bias)
{
  size_t row = blockIdx.x;
  float* p = logits + row * NTOK;
  float v[40];
  float mx = -1e30f;
  #pragma unroll
  for (int i=0;i<40;i++){
    int c = threadIdx.x + (i<<8);
    float x = (c < NTOK) ? (p[c] + bias[c]) : -1e30f;
    v[i] = x; mx = fmaxf(mx, x);
  }
  #pragma unroll
  for (int off=32; off>0; off>>=1) mx = fmaxf(mx, __shfl_down(mx, off));
  __shared__ float red[4], red2[4];
  int wv = threadIdx.x>>6, ln = threadIdx.x&63;
  if (ln==0) red[wv] = mx;
  __syncthreads();
  mx = fmaxf(fmaxf(red[0],red[1]), fmaxf(red[2],red[3]));
  float s = 0.f;
  #pragma unroll
  for (int i=0;i<40;i++) s += __expf(v[i] - mx);
  #pragma unroll
  for (int off=32; off>0; off>>=1) s += __shfl_down(s, off);
  if (ln==0) red2[wv] = s;
  __syncthreads();
  s = red2[0]+red2[1]+red2[2]+red2[3];
  float lse = mx + __logf(s);
  #pragma unroll
  for (int i=0;i<40;i++){
    int c = threadIdx.x + (i<<8);
    if (c < NTOK) p[c] = v[i] - lse;
  }
}

__global__ void k_copy(const float* __restrict__ src, float* __restrict__ dst, int n){
  int i = blockIdx.x*blockDim.x + threadIdx.x;
  if (i < n) dst[i] = src[i];
}

// ---------------- launch ----------------

extern "C" void kernel_launch(void* const* d_in, const int* in_sizes, int n_in,
                              void* d_out, int out_size, void* d_ws, size_t ws_size,
                              hipStream_t stream) {
  const int*   tok  = (const int*)d_in[0];
  const float* h0   = (const float*)d_in[1];
  const float* encw = (const float*)d_in[2];
  const float* W0   = (const float*)d_in[3];
  const float* Ws   = (const float*)d_in[4];
  const float* decb = (const float*)d_in[5];
  float* out = (float*)d_out;

  char* w = (char*)d_ws;
  unsigned short* Wt      = (unsigned short*)w; w += (size_t)10*WMAT*2;
  unsigned short* encw_bf = (unsigned short*)w; w += (size_t)NTOK*NHID*2;
  unsigned short* h0_bf   = (unsigned short*)w; w += (size_t)BN*2;
  unsigned short* hid_bf  = (unsigned short*)w; w += (size_t)TT*BN*2;
  float*          st_f    = (float*)w;          w += (size_t)9*BN*4;
  unsigned short* st_bf   = (unsigned short*)w; w += (size_t)9*BN*2;
  float*          h_f     = (float*)w;          w += (size_t)BN*4;
  unsigned short* h_bf    = (unsigned short*)w; w += (size_t)BN*2;
  unsigned*       flags   = (unsigned*)w;       w += (size_t)576*FSTRIDE*4;

  k_zero<<<36, 256, 0, stream>>>(flags, 576*FSTRIDE);
  k_transpose_cvt<<<dim3(64,32,10), 256, 0, stream>>>(W0, Ws, Wt);
  k_cvt<<<4096, 256, 0, stream>>>(encw, encw_bf, NTOK*NHID);
  k_cvt<<<128, 256, 0, stream>>>(h0, h0_bf, BN);

  k_recur<<<256, 256, 0, stream>>>(tok, h0, encw_bf, Wt, h0_bf,
                                   st_f, st_bf, h_f, h_bf, hid_bf, flags);

  k_decoder<<<dim3(157,64), 256, 0, stream>>>(hid_bf, encw_bf, out);
  k_logsoftmax<<<TT*BB, 256, 0, stream>>>(out, decb);
  k_copy<<<128, 256, 0, stream>>>(h_f, out + (size_t)TT*BB*NTOK, BN);
}

// Round 4
// 4613.972 us; speedup vs baseline: 2.0865x; 1.1616x over previous
//
#include <hip/hip_runtime.h>
#include <cmath>

#define NHID 1024
#define NTOK 10000
#define TT 128
#define BB 32
#define BN (BB*NHID)            // elems per (B,NHID) state
#define WMAT (2048*1024)        // elems per transposed weight matrix
#define FSTRIDE 16              // flag padding: 16 dwords = 64B per flag

typedef __attribute__((ext_vector_type(8))) short s8v;   // 8 x bf16 raw
typedef __attribute__((ext_vector_type(4))) float f4v;   // MFMA accumulator

#define MFMA(a,b,c) __builtin_amdgcn_mfma_f32_16x16x32_bf16(a,b,c,0,0,0)

__device__ __forceinline__ float sigf(float x){ return 1.f/(1.f+__expf(-x)); }
__device__ __forceinline__ float actf(int a, float h){
  switch(a){ case 0: return sigf(h); case 1: return fmaxf(h,0.f);
             case 2: return tanhf(h); default: return h; }
}
__device__ __forceinline__ unsigned short f2bf(float x){
  union { float f; unsigned u; } v; v.f = x;
  unsigned r = v.u + 0x7fffu + ((v.u >> 16) & 1u);
  return (unsigned short)(r >> 16);
}

// coherent 16B state load as two 64-bit relaxed agent atomic loads
// (compiler-visible -> spill-safe; reads the L3 coherence point)
__device__ __forceinline__ s8v ld_a16(const unsigned short* p){
  union { unsigned long long u[2]; s8v v; } x;
  x.u[0] = __hip_atomic_load((const unsigned long long*)p,
                             __ATOMIC_RELAXED, __HIP_MEMORY_SCOPE_AGENT);
  x.u[1] = __hip_atomic_load(((const unsigned long long*)p)+1,
                             __ATOMIC_RELAXED, __HIP_MEMORY_SCOPE_AGENT);
  return x.v;
}
__device__ __forceinline__ void ld_f2(const float* p, float& x0, float& x1){
  unsigned long long u = __hip_atomic_load((const unsigned long long*)p,
                         __ATOMIC_RELAXED, __HIP_MEMORY_SCOPE_AGENT);
  union { unsigned long long u; float f[2]; } v; v.u = u;
  x0 = v.f[0]; x1 = v.f[1];
}

// ---- write-through stores: data goes straight to the L3 coherence point,
// so NO dirty L2 lines exist for shared buffers and NO buffer_wbl2 (the
// per-hop ~thousands-of-cycles L2 tag walk in agent-RELEASE) is ever needed.
// vmcnt(0) after these = ACKed at coherence point. Asm stores are input-only
// (no spill hazard, unlike the Round-2 asm loads).
__device__ __forceinline__ void st_wt32(void* p, unsigned x){
  asm volatile("global_store_dword %0, %1, off sc0 sc1" :: "v"(p), "v"(x) : "memory");
}
__device__ __forceinline__ void st_wt64(void* p, unsigned long long x){
  asm volatile("global_store_dwordx2 %0, %1, off sc0 sc1" :: "v"(p), "v"(x) : "memory");
}
__device__ __forceinline__ unsigned long long packf2(float a, float b){
  union { float f[2]; unsigned long long u; } v; v.f[0]=a; v.f[1]=b; return v.u;
}

// ---------------- prep kernels ----------------

__global__ __launch_bounds__(256) void k_transpose_cvt(
    const float* __restrict__ W0, const float* __restrict__ Ws,
    unsigned short* __restrict__ dstAll)
{
  int z = blockIdx.z;
  const float* src = (z==0) ? W0 : (z==1) ? (W0 + (size_t)1024*2048)
                                          : (Ws + (size_t)(z-2)*1024*2048);
  unsigned short* dst = dstAll + (size_t)z*WMAT;
  __shared__ float tile[32][33];
  int n0 = blockIdx.x*32;
  int k0 = blockIdx.y*32;
  int tx = threadIdx.x & 31, ty = threadIdx.x >> 5;
  #pragma unroll
  for (int i=0;i<4;i++){
    int k = k0 + ty + i*8;
    tile[ty + i*8][tx] = src[(size_t)k*2048 + n0 + tx];
  }
  __syncthreads();
  #pragma unroll
  for (int i=0;i<4;i++){
    int n = n0 + ty + i*8;
    dst[(size_t)n*1024 + k0 + tx] = f2bf(tile[tx][ty + i*8]);
  }
}

__global__ void k_cvt(const float* __restrict__ src, unsigned short* __restrict__ dst, int n){
  int i = blockIdx.x*blockDim.x + threadIdx.x;
  int stride = gridDim.x*blockDim.x;
  for (; i < n; i += stride) dst[i] = f2bf(src[i]);
}

__global__ void k_zero(unsigned* __restrict__ p, int n){
  int i = blockIdx.x*blockDim.x + threadIdx.x;
  if (i < n) p[i] = 0u;
}

// ---------------- persistent recurrence kernel ----------------
// grid = 256 WGs x 256 threads (4 waves), 1 per CU, all co-resident.
// Sync design (v4):
//  * all cross-WG data stores are write-through sc0+sc1 -> no wbl2/inv
//    anywhere in the loop. signal = per-wave vmcnt(0) drain + __syncthreads
//    + one WT flag store.
//  * per-WAVE need-based polling: each wave polls only the 16 producer tiles
//    covering its K-chunk (+1 for this WG's own tile, read in the epilogue),
//    with NO barrier before the loads -> waves start as their slice is ready.

__device__ __forceinline__ void poll1(const unsigned* F, int idx, unsigned tgt){
  const unsigned* f = F + (size_t)idx*FSTRIDE;
  while (__hip_atomic_load(f, __ATOMIC_RELAXED, __HIP_MEMORY_SCOPE_AGENT) < tgt)
    __builtin_amdgcn_s_sleep(1);
}
__device__ __forceinline__ void signal(unsigned* F, int s, int tile, unsigned val){
  asm volatile("s_waitcnt vmcnt(0)" ::: "memory");  // this wave's WT stores ACKed at L3
  __syncthreads();                                   // all waves likewise
  if (threadIdx.x == 0)
    st_wt32((void*)(F + (size_t)((s<<6)+tile)*FSTRIDE), val);
}

struct B8  { s8v c[8];  s8v h[8];  };   //  64 VGPRs: one edge task, K=256/wave
struct B16 { s8v c[16]; s8v h[16]; };   // 128 VGPRs: L1 (K=512/wave)

__device__ __forceinline__ void load_b8(const unsigned short* __restrict__ Wt,
                                        int z, int j0, int r, int kb, int q, B8& B){
  const unsigned short* wz = Wt + (size_t)z*WMAT;
  const s8v* bc = (const s8v*)(wz + (size_t)(j0+r)*1024 + kb);
  const s8v* bh = (const s8v*)(wz + (size_t)(1024+j0+r)*1024 + kb);
  #pragma unroll
  for (int i=0;i<8;i++){ B.c[i]=bc[q+4*i]; B.h[i]=bh[q+4*i]; }
}

// one edge task with weights in registers: 16 paired cols (tile j0),
// K=1024 split 4 ways over waves
__device__ __forceinline__ void do_edge_reg(
    const B8& B, float* __restrict__ st_f,
    unsigned short* __restrict__ st_bf, float* __restrict__ red,
    unsigned* __restrict__ F, int pred, int outs, int act,
    int j0, int tile, unsigned tgt, int wave, int q, int r, int tid)
{
  int lane = tid & 63;
  // per-wave wait: 16 K-chunk producer tiles + own tile (epilogue f32 read)
  if (lane < 17){
    int idx = (pred<<6) + ((lane<16) ? (wave*16 + lane) : tile);
    poll1(F, idx, tgt);
  }
  int row = tid>>3, col = (tid&7)*2;
  size_t off = (size_t)row*NHID + j0 + col;
  float sp0, sp1;                                  // epilogue operand: prefetch
  ld_f2(st_f + (size_t)pred*BN + off, sp0, sp1);   // early, hides under MFMAs
  const unsigned short* spb = st_bf + (size_t)pred*BN;
  int kb = wave*256;
  const unsigned short* p0 = spb + (size_t)r*NHID + kb;
  const unsigned short* p1 = spb + (size_t)(16+r)*NHID + kb;
  s8v a0[8], a1[8];
  #pragma unroll
  for (int i=0;i<8;i++){
    a0[i] = ld_a16(p0 + (q+4*i)*8);
    a1[i] = ld_a16(p1 + (q+4*i)*8);
  }
  f4v zz = {0.f,0.f,0.f,0.f};
  f4v aC0=zz,aC1=zz,aH0=zz,aH1=zz;
  #pragma unroll
  for (int i=0;i<8;i++){
    aC0=MFMA(a0[i],B.c[i],aC0); aC1=MFMA(a1[i],B.c[i],aC1);
    aH0=MFMA(a0[i],B.h[i],aH0); aH1=MFMA(a1[i],B.h[i],aH1);
  }
  #pragma unroll
  for (int i=0;i<4;i++){
    red[((wave*4+0)*32 + q*4+i)*16 + r]    = aC0[i];
    red[((wave*4+0)*32 + 16+q*4+i)*16 + r] = aC1[i];
    red[((wave*4+1)*32 + q*4+i)*16 + r]    = aH0[i];
    red[((wave*4+1)*32 + 16+q*4+i)*16 + r] = aH1[i];
  }
  __syncthreads();
  float cs0=0,cs1=0,hs0=0,hs1=0;
  #pragma unroll
  for (int w2=0; w2<4; w2++){
    cs0 += red[((w2*4+0)*32+row)*16+col];
    cs1 += red[((w2*4+0)*32+row)*16+col+1];
    hs0 += red[((w2*4+1)*32+row)*16+col];
    hs1 += red[((w2*4+1)*32+row)*16+col+1];
  }
  float v0 = sp0 + sigf(cs0)*(actf(act,hs0) - sp0);
  float v1 = sp1 + sigf(cs1)*(actf(act,hs1) - sp1);
  st_wt64(&st_f[(size_t)outs*BN+off], packf2(v0, v1));
  unsigned pk = (unsigned)f2bf(v0) | ((unsigned)f2bf(v1)<<16);
  st_wt32((unsigned*)(st_bf + (size_t)outs*BN + off), pk);
  signal(F, outs, tile, tgt);
}

__global__ __launch_bounds__(256, 1) void k_recur(
    const int* __restrict__ tok, const float* __restrict__ h0f,
    const unsigned short* __restrict__ encb,
    const unsigned short* __restrict__ Wt,
    const unsigned short* __restrict__ h0b,
    float* __restrict__ st_f, unsigned short* __restrict__ st_bf,
    float* __restrict__ h_f, unsigned short* __restrict__ h_bf,
    unsigned short* __restrict__ hid_bf, unsigned* __restrict__ F)
{
  __shared__ float red[4*4*32*16];   // 32 KB: [wave][ch up to 4][row 32][col 16]
  int wg = blockIdx.x, grp = wg >> 6, tile = wg & 63;
  int tid = threadIdx.x, wave = tid>>6, lane = tid&63, q = lane>>4, r = lane&15;
  int j0 = tile * 16;

  if (grp == 0) {
    // ---- weights resident in VGPRs for the whole kernel ----
    B16 BL;   // L1 init matmul; wave-specific K-chunk of the 2048-deep W0
    {
      const unsigned short* wz = Wt + (size_t)(wave>>1)*WMAT;
      int kloc = (wave & 1) * 512;
      const s8v* bc = (const s8v*)(wz + (size_t)(j0+r)*1024 + kloc);
      const s8v* bh = (const s8v*)(wz + (size_t)(1024+j0+r)*1024 + kloc);
      #pragma unroll
      for (int i=0;i<16;i++){ BL.c[i]=bc[q+4*i]; BL.h[i]=bh[q+4*i]; }
    }
    B8 B3; load_b8(Wt, 5, j0, r, wave*256, q, B3);   // e3: identity, s1->s4

    for (int t = 0; t < TT; ++t) {
      unsigned tgt = t+1;
      // ---- L1: init (K=2048: waves 0-1 take x half, 2-3 take h half) ----
      // issue static embedding A-operand loads BEFORE waiting on h(t-1):
      // plain cached loads (read-only data), latency hides under the poll
      s8v xa0[16], xa1[16];
      if (wave < 2){
        int kb = wave * 512;
        const s8v* e0p = (const s8v*)(encb + (size_t)tok[t*BB + r]*NHID + kb);
        const s8v* e1p = (const s8v*)(encb + (size_t)tok[t*BB + 16 + r]*NHID + kb);
        #pragma unroll
        for (int i=0;i<16;i++){ xa0[i]=e0p[q+4*i]; xa1[i]=e1p[q+4*i]; }
      }
      if (t) {
        // per-wave wait on h(t-1): waves 0-1 only need own tile (epilogue);
        // waves 2-3 need their 32 K-chunk tiles + own tile
        if (wave < 2){
          if (lane == 0) poll1(F, (8<<6)+tile, t);
        } else {
          if (lane < 33){
            int idx = (8<<6) + ((lane<32) ? ((wave-2)*32 + lane) : tile);
            poll1(F, idx, t);
          }
        }
      }
      int row = tid>>3, col = (tid&7)*2;
      size_t off = (size_t)row*NHID + j0 + col;
      const float* hfb = t ? h_f : h0f;
      float hp0, hp1; ld_f2(hfb + off, hp0, hp1);
      f4v zz = {0.f,0.f,0.f,0.f};
      f4v aC0=zz,aC1=zz,aH0=zz,aH1=zz;
      if (wave < 2) {
        #pragma unroll
        for (int i=0;i<16;i++){
          s8v a0=xa0[i], a1=xa1[i];
          aC0=MFMA(a0,BL.c[i],aC0); aC1=MFMA(a1,BL.c[i],aC1);
          aH0=MFMA(a0,BL.h[i],aH0); aH1=MFMA(a1,BL.h[i],aH1);
        }
      } else {
        const unsigned short* hb = t ? h_bf : h0b;
        int kb = (wave-2)*512;
        const unsigned short* g0 = hb + (size_t)r*NHID + kb;
        const unsigned short* g1 = hb + (size_t)(16+r)*NHID + kb;
        s8v ha0[16], ha1[16];
        #pragma unroll
        for (int i=0;i<16;i++){ ha0[i]=ld_a16(g0+(q+4*i)*8); ha1[i]=ld_a16(g1+(q+4*i)*8); }
        #pragma unroll
        for (int i=0;i<16;i++){
          aC0=MFMA(ha0[i],BL.c[i],aC0); aC1=MFMA(ha1[i],BL.c[i],aC1);
          aH0=MFMA(ha0[i],BL.h[i],aH0); aH1=MFMA(ha1[i],BL.h[i],aH1);
        }
      }
      #pragma unroll
      for (int i=0;i<4;i++){
        red[((wave*4+0)*32 + q*4+i)*16 + r]    = aC0[i];
        red[((wave*4+0)*32 + 16+q*4+i)*16 + r] = aC1[i];
        red[((wave*4+1)*32 + q*4+i)*16 + r]    = aH0[i];
        red[((wave*4+1)*32 + 16+q*4+i)*16 + r] = aH1[i];
      }
      __syncthreads();
      float cs0=0,cs1=0,hs0=0,hs1=0;
      #pragma unroll
      for (int w2=0; w2<4; w2++){
        cs0 += red[((w2*4+0)*32+row)*16+col];
        cs1 += red[((w2*4+0)*32+row)*16+col+1];
        hs0 += red[((w2*4+1)*32+row)*16+col];
        hs1 += red[((w2*4+1)*32+row)*16+col+1];
      }
      float v0 = hp0 + sigf(cs0)*(tanhf(hs0)-hp0);
      float v1 = hp1 + sigf(cs1)*(tanhf(hs1)-hp1);
      st_wt64(&st_f[off], packf2(v0, v1));
      unsigned pk = (unsigned)f2bf(v0) | ((unsigned)f2bf(v1)<<16);
      st_wt32((unsigned*)(st_bf + off), pk);
      signal(F, 0, tile, tgt);
      // ---- e3 (identity, pred s1, out s4) ----
      do_edge_reg(B3, st_f, st_bf, red, F, 1, 4, 3, j0, tile, tgt, wave, q, r, tid);
    }
  } else if (grp == 1) {
    B8 B0; load_b8(Wt, 2, j0, r, wave*256, q, B0);   // e0: sigmoid, s0->s1
    B8 B4; load_b8(Wt, 6, j0, r, wave*256, q, B4);   // e4: tanh,    s2->s5
    for (int t = 0; t < TT; ++t) {
      unsigned tgt = t+1;
      do_edge_reg(B0, st_f, st_bf, red, F, 0, 1, 0, j0, tile, tgt, wave, q, r, tid);
      do_edge_reg(B4, st_f, st_bf, red, F, 2, 5, 2, j0, tile, tgt, wave, q, r, tid);
    }
  } else if (grp == 2) {
    B8 B1; load_b8(Wt, 3, j0, r, wave*256, q, B1);   // e1: relu, s1->s2
    B8 B6; load_b8(Wt, 8, j0, r, wave*256, q, B6);   // e6: tanh, s3->s7
    for (int t = 0; t < TT; ++t) {
      unsigned tgt = t+1;
      do_edge_reg(B1, st_f, st_bf, red, F, 1, 2, 1, j0, tile, tgt, wave, q, r, tid);
      do_edge_reg(B6, st_f, st_bf, red, F, 3, 7, 2, j0, tile, tgt, wave, q, r, tid);
    }
  } else {
    B8 B2; load_b8(Wt, 4, j0, r, wave*256, q, B2);   // e2: relu, s1->s3
    B8 B5; load_b8(Wt, 7, j0, r, wave*256, q, B5);   // e5: sigmoid, s5->s6
    B8 B7; load_b8(Wt, 9, j0, r, wave*256, q, B7);   // e7: relu,    s5->s8
    for (int t = 0; t < TT; ++t) {
      unsigned tgt = t+1;
      // ---- e2 (relu, pred s1, out s3) ----
      do_edge_reg(B2, st_f, st_bf, red, F, 1, 3, 1, j0, tile, tgt, wave, q, r, tid);
      // ---- fused e5 (sigmoid) + e7 (relu), pred s5; compute mean h ----
      // per-wave wait: s5 K-chunk tiles for the MFMA; own-tile flags of
      // s4/s5/s7 for the epilogue (transitively imply s1,s2,s3 complete)
      if (lane < 19){
        int idx = (lane<16) ? ((5<<6) + wave*16 + lane)
                : (lane==16) ? ((4<<6)+tile)
                : (lane==17) ? ((5<<6)+tile) : ((7<<6)+tile);
        poll1(F, idx, tgt);
      }
      {
        int row = tid>>3, col = (tid&7)*2;
        size_t off = (size_t)row*NHID + j0 + col;
        float s1a,s1b,s2a,s2b,s3a,s3b,s4a,s4b,s5a,s5b,s7a,s7b;
        ld_f2(st_f + (size_t)1*BN + off, s1a, s1b);
        ld_f2(st_f + (size_t)2*BN + off, s2a, s2b);
        ld_f2(st_f + (size_t)3*BN + off, s3a, s3b);
        ld_f2(st_f + (size_t)4*BN + off, s4a, s4b);
        ld_f2(st_f + (size_t)5*BN + off, s5a, s5b);
        ld_f2(st_f + (size_t)7*BN + off, s7a, s7b);
        const unsigned short* spb = st_bf + (size_t)5*BN;
        int kb = wave*256;
        const unsigned short* p0 = spb + (size_t)r*NHID + kb;
        const unsigned short* p1 = spb + (size_t)(16+r)*NHID + kb;
        s8v a0[8], a1[8];
        #pragma unroll
        for (int i=0;i<8;i++){ a0[i]=ld_a16(p0+(q+4*i)*8); a1[i]=ld_a16(p1+(q+4*i)*8); }
        f4v zz = {0.f,0.f,0.f,0.f};
        f4v c50=zz,c51=zz,h50=zz,h51=zz,c70=zz,c71=zz,h70=zz,h71=zz;
        #pragma unroll
        for (int i=0;i<8;i++){
          c50=MFMA(a0[i],B5.c[i],c50); c51=MFMA(a1[i],B5.c[i],c51);
          h50=MFMA(a0[i],B5.h[i],h50); h51=MFMA(a1[i],B5.h[i],h51);
          c70=MFMA(a0[i],B7.c[i],c70); c71=MFMA(a1[i],B7.c[i],c71);
          h70=MFMA(a0[i],B7.h[i],h70); h71=MFMA(a1[i],B7.h[i],h71);
        }
        #pragma unroll
        for (int i=0;i<4;i++){
          red[((wave*4+0)*32 + q*4+i)*16 + r]    = c50[i];
          red[((wave*4+0)*32 + 16+q*4+i)*16 + r] = c51[i];
          red[((wave*4+1)*32 + q*4+i)*16 + r]    = h50[i];
          red[((wave*4+1)*32 + 16+q*4+i)*16 + r] = h51[i];
          red[((wave*4+2)*32 + q*4+i)*16 + r]    = c70[i];
          red[((wave*4+2)*32 + 16+q*4+i)*16 + r] = c71[i];
          red[((wave*4+3)*32 + q*4+i)*16 + r]    = h70[i];
          red[((wave*4+3)*32 + 16+q*4+i)*16 + r] = h71[i];
        }
        __syncthreads();
        float a5c[2]={0,0}, a5h[2]={0,0}, a7c[2]={0,0}, a7h[2]={0,0};
        #pragma unroll
        for (int w2=0; w2<4; w2++){
          #pragma unroll
          for (int u=0; u<2; u++){
            a5c[u] += red[((w2*4+0)*32+row)*16+col+u];
            a5h[u] += red[((w2*4+1)*32+row)*16+col+u];
            a7c[u] += red[((w2*4+2)*32+row)*16+col+u];
            a7h[u] += red[((w2*4+3)*32+row)*16+col+u];
          }
        }
        float s5v[2] = {s5a, s5b};
        float o1[2] = {s1a, s1b}, o2[2] = {s2a, s2b}, o3[2] = {s3a, s3b};
        float o4[2] = {s4a, s4b}, o7[2] = {s7a, s7b};
        float hv[2];
        #pragma unroll
        for (int u=0; u<2; u++){
          float s5j = s5v[u];
          float s6 = s5j + sigf(a5c[u])*(sigf(a5h[u]) - s5j);
          float s8 = s5j + sigf(a7c[u])*(fmaxf(a7h[u],0.f) - s5j);
          float sum = o1[u] + o2[u] + o3[u] + o4[u]
                    + s5j + s6 + o7[u] + s8;
          hv[u] = 0.125f * sum;
        }
        st_wt64(&h_f[off], packf2(hv[0], hv[1]));
        unsigned pk = (unsigned)f2bf(hv[0]) | ((unsigned)f2bf(hv[1])<<16);
        st_wt32((unsigned*)(h_bf + off), pk);
        *(unsigned*)(hid_bf + (size_t)t*BN + off) = pk;   // consumed post-kernel
        signal(F, 8, tile, tgt);
      }
    }
  }
}

// ---------------- decoder ----------------

__global__ __launch_bounds__(256) void k_decoder(
    const unsigned short* __restrict__ Hb, const unsigned short* __restrict__ Wb,
    float* __restrict__ out)
{
  int wave = threadIdx.x >> 6, lane = threadIdx.x & 63;
  int q = lane >> 4, r = lane & 15;
  int bm = blockIdx.y*64 + (wave>>1)*32;
  int bn = blockIdx.x*64 + (wave&1)*32;
  f4v z = {0.f,0.f,0.f,0.f};
  f4v acc00=z, acc01=z, acc10=z, acc11=z;
  const s8v* a0p = (const s8v*)(Hb + (size_t)(bm + r)*NHID);
  const s8v* a1p = (const s8v*)(Hb + (size_t)(bm + 16 + r)*NHID);
  int n0 = bn + r, n1 = bn + 16 + r;
  const s8v* b0p = (const s8v*)(Wb + (size_t)(n0 < NTOK ? n0 : 0)*NHID);
  const s8v* b1p = (const s8v*)(Wb + (size_t)(n1 < NTOK ? n1 : 0)*NHID);
  #pragma unroll 4
  for (int v = q; v < 128; v += 4) {
    s8v a0 = a0p[v], a1 = a1p[v], b0 = b0p[v], b1 = b1p[v];
    acc00 = MFMA(a0, b0, acc00); acc10 = MFMA(a1, b0, acc10);
    acc01 = MFMA(a0, b1, acc01); acc11 = MFMA(a1, b1, acc11);
  }
  #pragma unroll
  for (int ni=0; ni<2; ni++){
    int col = bn + ni*16 + r;
    if (col >= NTOK) continue;
    #pragma unroll
    for (int mi=0; mi<2; mi++){
      f4v a = (mi==0) ? (ni==0 ? acc00 : acc01) : (ni==0 ? acc10 : acc11);
      #pragma unroll
      for (int t4=0; t4<4; t4++){
        int row = bm + mi*16 + q*4 + t4;
        out[(size_t)row*NTOK + col] = a[t4];
      }
    }
  }
}

__global__ __launch_bounds__(256) void k_logsoftmax(
    float* __restrict__ logits, const float* __restrict__ bias)
{
  size_t row = blockIdx.x;
  float* p = logits + row * NTOK;
  float v[40];
  float mx = -1e30f;
  #pragma unroll
  for (int i=0;i<40;i++){
    int c = threadIdx.x + (i<<8);
    float x = (c < NTOK) ? (p[c] + bias[c]) : -1e30f;
    v[i] = x; mx = fmaxf(mx, x);
  }
  #pragma unroll
  for (int off=32; off>0; off>>=1) mx = fmaxf(mx, __shfl_down(mx, off));
  __shared__ float red[4], red2[4];
  int wv = threadIdx.x>>6, ln = threadIdx.x&63;
  if (ln==0) red[wv] = mx;
  __syncthreads();
  mx = fmaxf(fmaxf(red[0],red[1]), fmaxf(red[2],red[3]));
  float s = 0.f;
  #pragma unroll
  for (int i=0;i<40;i++) s += __expf(v[i] - mx);
  #pragma unroll
  for (int off=32; off>0; off>>=1) s += __shfl_down(s, off);
  if (ln==0) red2[wv] = s;
  __syncthreads();
  s = red2[0]+red2[1]+red2[2]+red2[3];
  float lse = mx + __logf(s);
  #pragma unroll
  for (int i=0;i<40;i++){
    int c = threadIdx.x + (i<<8);
    if (c < NTOK) p[c] = v[i] - lse;
  }
}

__global__ void k_copy(const float* __restrict__ src, float* __restrict__ dst, int n){
  int i = blockIdx.x*blockDim.x + threadIdx.x;
  if (i < n) dst[i] = src[i];
}

// ---------------- launch ----------------

extern "C" void kernel_launch(void* const* d_in, const int* in_sizes, int n_in,
                              void* d_out, int out_size, void* d_ws, size_t ws_size,
                              hipStream_t stream) {
  const int*   tok  = (const int*)d_in[0];
  const float* h0   = (const float*)d_in[1];
  const float* encw = (const float*)d_in[2];
  const float* W0   = (const float*)d_in[3];
  const float* Ws   = (const float*)d_in[4];
  const float* decb = (const float*)d_in[5];
  float* out = (float*)d_out;

  char* w = (char*)d_ws;
  unsigned short* Wt      = (unsigned short*)w; w += (size_t)10*WMAT*2;
  unsigned short* encw_bf = (unsigned short*)w; w += (size_t)NTOK*NHID*2;
  unsigned short* h0_bf   = (unsigned short*)w; w += (size_t)BN*2;
  unsigned short* hid_bf  = (unsigned short*)w; w += (size_t)TT*BN*2;
  float*          st_f    = (float*)w;          w += (size_t)9*BN*4;
  unsigned short* st_bf   = (unsigned short*)w; w += (size_t)9*BN*2;
  float*          h_f     = (float*)w;          w += (size_t)BN*4;
  unsigned short* h_bf    = (unsigned short*)w; w += (size_t)BN*2;
  unsigned*       flags   = (unsigned*)w;       w += (size_t)576*FSTRIDE*4;

  k_zero<<<36, 256, 0, stream>>>(flags, 576*FSTRIDE);
  k_transpose_cvt<<<dim3(64,32,10), 256, 0, stream>>>(W0, Ws, Wt);
  k_cvt<<<4096, 256, 0, stream>>>(encw, encw_bf, NTOK*NHID);
  k_cvt<<<128, 256, 0, stream>>>(h0, h0_bf, BN);

  k_recur<<<256, 256, 0, stream>>>(tok, h0, encw_bf, Wt, h0_bf,
                                   st_f, st_bf, h_f, h_bf, hid_bf, flags);

  k_decoder<<<dim3(157,64), 256, 0, stream>>>(hid_bf, encw_bf, out);
  k_logsoftmax<<<TT*BB, 256, 0, stream>>>(out, decb);
  k_copy<<<128, 256, 0, stream>>>(h_f, out + (size_t)TT*BB*NTOK, BN);
}

// Round 5
// 3553.330 us; speedup vs baseline: 2.7093x; 1.2985x over previous
//
#include <hip/hip_runtime.h>
#include <cmath>

#define NHID 1024
#define NTOK 10000
#define TT 128
#define BB 32
#define BN (BB*NHID)            // elems per (B,NHID) state
#define WMAT (2048*1024)        // elems per transposed weight matrix
#define FSTRIDE 16              // flag padding: 16 dwords = 64B per flag

typedef __attribute__((ext_vector_type(8))) short s8v;   // 8 x bf16 raw
typedef __attribute__((ext_vector_type(4))) float f4v;   // MFMA accumulator

#define MFMA(a,b,c) __builtin_amdgcn_mfma_f32_16x16x32_bf16(a,b,c,0,0,0)

__device__ __forceinline__ float sigf(float x){ return 1.f/(1.f+__expf(-x)); }
__device__ __forceinline__ float actf(int a, float h){
  switch(a){ case 0: return sigf(h); case 1: return fmaxf(h,0.f);
             case 2: return tanhf(h); default: return h; }
}
__device__ __forceinline__ unsigned short f2bf(float x){
  union { float f; unsigned u; } v; v.f = x;
  unsigned r = v.u + 0x7fffu + ((v.u >> 16) & 1u);
  return (unsigned short)(r >> 16);
}

__device__ __forceinline__ void ld_f2(const float* p, float& x0, float& x1){
  unsigned long long u = __hip_atomic_load((const unsigned long long*)p,
                         __ATOMIC_RELAXED, __HIP_MEMORY_SCOPE_AGENT);
  union { unsigned long long u; float f[2]; } v; v.u = u;
  x0 = v.f[0]; x1 = v.f[1];
}

// ---- coherent bulk A-load: 16x dwordx4 sc0+sc1 (L3 read, L2-bypass) in ONE
// asm block with the s_waitcnt INSIDE. Outputs are defined only at asm end,
// so the compiler cannot spill/copy an in-flight destination (the R2 hazard).
// 16B granules halve the L3 request count vs the previous 8B atomic loads —
// the hop-dominant burst (131k requests/hop grid-wide) is request-rate bound.
__device__ __forceinline__ void coh_ld16(const unsigned short* pa, const unsigned short* pb,
                                         s8v A[8], s8v B[8]){
  asm volatile(
    "global_load_dwordx4 %0, %16, off sc0 sc1\n\t"
    "global_load_dwordx4 %1, %16, off offset:64 sc0 sc1\n\t"
    "global_load_dwordx4 %2, %16, off offset:128 sc0 sc1\n\t"
    "global_load_dwordx4 %3, %16, off offset:192 sc0 sc1\n\t"
    "global_load_dwordx4 %4, %16, off offset:256 sc0 sc1\n\t"
    "global_load_dwordx4 %5, %16, off offset:320 sc0 sc1\n\t"
    "global_load_dwordx4 %6, %16, off offset:384 sc0 sc1\n\t"
    "global_load_dwordx4 %7, %16, off offset:448 sc0 sc1\n\t"
    "global_load_dwordx4 %8, %17, off sc0 sc1\n\t"
    "global_load_dwordx4 %9, %17, off offset:64 sc0 sc1\n\t"
    "global_load_dwordx4 %10, %17, off offset:128 sc0 sc1\n\t"
    "global_load_dwordx4 %11, %17, off offset:192 sc0 sc1\n\t"
    "global_load_dwordx4 %12, %17, off offset:256 sc0 sc1\n\t"
    "global_load_dwordx4 %13, %17, off offset:320 sc0 sc1\n\t"
    "global_load_dwordx4 %14, %17, off offset:384 sc0 sc1\n\t"
    "global_load_dwordx4 %15, %17, off offset:448 sc0 sc1\n\t"
    "s_waitcnt vmcnt(0)"
    : "=&v"(A[0]),"=&v"(A[1]),"=&v"(A[2]),"=&v"(A[3]),
      "=&v"(A[4]),"=&v"(A[5]),"=&v"(A[6]),"=&v"(A[7]),
      "=&v"(B[0]),"=&v"(B[1]),"=&v"(B[2]),"=&v"(B[3]),
      "=&v"(B[4]),"=&v"(B[5]),"=&v"(B[6]),"=&v"(B[7])
    : "v"(pa), "v"(pb)
    : "memory");
}

// write-through stores (straight to L3 coherence point; no dirty L2 lines,
// no wbl2 needed anywhere). Input-only asm: no spill hazard.
__device__ __forceinline__ void st_wt32(void* p, unsigned x){
  asm volatile("global_store_dword %0, %1, off sc0 sc1" :: "v"(p), "v"(x) : "memory");
}
__device__ __forceinline__ void st_wt64(void* p, unsigned long long x){
  asm volatile("global_store_dwordx2 %0, %1, off sc0 sc1" :: "v"(p), "v"(x) : "memory");
}
__device__ __forceinline__ unsigned long long packf2(float a, float b){
  union { float f[2]; unsigned long long u; } v; v.f[0]=a; v.f[1]=b; return v.u;
}

// ---------------- prep kernels ----------------

__global__ __launch_bounds__(256) void k_transpose_cvt(
    const float* __restrict__ W0, const float* __restrict__ Ws,
    unsigned short* __restrict__ dstAll)
{
  int z = blockIdx.z;
  const float* src = (z==0) ? W0 : (z==1) ? (W0 + (size_t)1024*2048)
                                          : (Ws + (size_t)(z-2)*1024*2048);
  unsigned short* dst = dstAll + (size_t)z*WMAT;
  __shared__ float tile[32][33];
  int n0 = blockIdx.x*32;
  int k0 = blockIdx.y*32;
  int tx = threadIdx.x & 31, ty = threadIdx.x >> 5;
  #pragma unroll
  for (int i=0;i<4;i++){
    int k = k0 + ty + i*8;
    tile[ty + i*8][tx] = src[(size_t)k*2048 + n0 + tx];
  }
  __syncthreads();
  #pragma unroll
  for (int i=0;i<4;i++){
    int n = n0 + ty + i*8;
    dst[(size_t)n*1024 + k0 + tx] = f2bf(tile[tx][ty + i*8]);
  }
}

__global__ void k_cvt(const float* __restrict__ src, unsigned short* __restrict__ dst, int n){
  int i = blockIdx.x*blockDim.x + threadIdx.x;
  int stride = gridDim.x*blockDim.x;
  for (; i < n; i += stride) dst[i] = f2bf(src[i]);
}

__global__ void k_zero(unsigned* __restrict__ p, int n){
  int i = blockIdx.x*blockDim.x + threadIdx.x;
  if (i < n) p[i] = 0u;
}

// ---------------- persistent recurrence kernel ----------------
// grid = 256 WGs x 256 threads (4 waves), 1 per CU, all co-resident.
// Sync design (v5): per-(state,tile) WT flags (R4) + wide coherent loads +
// slower poll cadence to relieve L3 request-rate pressure.

__device__ __forceinline__ void poll1(const unsigned* F, int idx, unsigned tgt){
  const unsigned* f = F + (size_t)idx*FSTRIDE;
  while (__hip_atomic_load(f, __ATOMIC_RELAXED, __HIP_MEMORY_SCOPE_AGENT) < tgt)
    __builtin_amdgcn_s_sleep(2);
}
__device__ __forceinline__ void signal(unsigned* F, int s, int tile, unsigned val){
  asm volatile("s_waitcnt vmcnt(0)" ::: "memory");  // this wave's WT stores ACKed at L3
  __syncthreads();                                   // all waves likewise
  if (threadIdx.x == 0)
    st_wt32((void*)(F + (size_t)((s<<6)+tile)*FSTRIDE), val);
}

struct B8 { s8v c[8]; s8v h[8]; };   // 64 VGPRs: one task's B-frags, K=256/wave

__device__ __forceinline__ void load_b8(const unsigned short* __restrict__ Wt,
                                        int z, int j0, int r, int kb, int q, B8& B){
  const unsigned short* wz = Wt + (size_t)z*WMAT;
  const s8v* bc = (const s8v*)(wz + (size_t)(j0+r)*1024 + kb);
  const s8v* bh = (const s8v*)(wz + (size_t)(1024+j0+r)*1024 + kb);
  #pragma unroll
  for (int i=0;i<8;i++){ B.c[i]=bc[q+4*i]; B.h[i]=bh[q+4*i]; }
}

// one edge task with weights in registers: 16 paired cols (tile j0),
// K=1024 split 4 ways over waves; per-wave need-based polling
__device__ __forceinline__ void do_edge_reg(
    const B8& B, float* __restrict__ st_f,
    unsigned short* __restrict__ st_bf, float* __restrict__ red,
    unsigned* __restrict__ F, int pred, int outs, int act,
    int j0, int tile, unsigned tgt, int wave, int q, int r, int tid)
{
  int lane = tid & 63;
  if (lane < 17){
    int idx = (pred<<6) + ((lane<16) ? (wave*16 + lane) : tile);
    poll1(F, idx, tgt);
  }
  int row = tid>>3, col = (tid&7)*2;
  size_t off = (size_t)row*NHID + j0 + col;
  float sp0, sp1;                                  // epilogue operand: prefetch
  ld_f2(st_f + (size_t)pred*BN + off, sp0, sp1);
  const unsigned short* spb = st_bf + (size_t)pred*BN;
  int kb = wave*256;
  s8v a0[8], a1[8];
  coh_ld16(spb + (size_t)r*NHID + kb + q*8,
           spb + (size_t)(16+r)*NHID + kb + q*8, a0, a1);
  f4v zz = {0.f,0.f,0.f,0.f};
  f4v aC0=zz,aC1=zz,aH0=zz,aH1=zz;
  #pragma unroll
  for (int i=0;i<8;i++){
    aC0=MFMA(a0[i],B.c[i],aC0); aC1=MFMA(a1[i],B.c[i],aC1);
    aH0=MFMA(a0[i],B.h[i],aH0); aH1=MFMA(a1[i],B.h[i],aH1);
  }
  #pragma unroll
  for (int i=0;i<4;i++){
    red[((wave*4+0)*32 + q*4+i)*16 + r]    = aC0[i];
    red[((wave*4+0)*32 + 16+q*4+i)*16 + r] = aC1[i];
    red[((wave*4+1)*32 + q*4+i)*16 + r]    = aH0[i];
    red[((wave*4+1)*32 + 16+q*4+i)*16 + r] = aH1[i];
  }
  __syncthreads();
  float cs0=0,cs1=0,hs0=0,hs1=0;
  #pragma unroll
  for (int w2=0; w2<4; w2++){
    cs0 += red[((w2*4+0)*32+row)*16+col];
    cs1 += red[((w2*4+0)*32+row)*16+col+1];
    hs0 += red[((w2*4+1)*32+row)*16+col];
    hs1 += red[((w2*4+1)*32+row)*16+col+1];
  }
  float v0 = sp0 + sigf(cs0)*(actf(act,hs0) - sp0);
  float v1 = sp1 + sigf(cs1)*(actf(act,hs1) - sp1);
  st_wt64(&st_f[(size_t)outs*BN+off], packf2(v0, v1));
  unsigned pk = (unsigned)f2bf(v0) | ((unsigned)f2bf(v1)<<16);
  st_wt32((unsigned*)(st_bf + (size_t)outs*BN + off), pk);
  signal(F, outs, tile, tgt);
}

__global__ __launch_bounds__(256, 1) void k_recur(
    const int* __restrict__ tok, const float* __restrict__ h0f,
    const unsigned short* __restrict__ encb,
    const unsigned short* __restrict__ Wt,
    const unsigned short* __restrict__ h0b,
    float* __restrict__ st_f, unsigned short* __restrict__ st_bf,
    float* __restrict__ h_f, unsigned short* __restrict__ h_bf,
    unsigned short* __restrict__ hid_bf, unsigned* __restrict__ F)
{
  __shared__ float red[4*4*32*16];   // 32 KB
  int wg = blockIdx.x, grp = wg >> 6, tile = wg & 63;
  int tid = threadIdx.x, wave = tid>>6, lane = tid&63, q = lane>>4, r = lane&15;
  int j0 = tile * 16;

  if (grp == 0) {
    // ---- L1 restructure (v5): every wave takes K=256 of x AND K=256 of h.
    // x B-frags from Wt[0] (W0 rows 0..1023), h B-frags from Wt[1].
    // Makes L1's h-dependent load chain identical in shape to do_edge.
    B8 BX; load_b8(Wt, 0, j0, r, wave*256, q, BX);
    B8 BH; load_b8(Wt, 1, j0, r, wave*256, q, BH);
    B8 B3; load_b8(Wt, 5, j0, r, wave*256, q, B3);   // e3: identity, s1->s4

    for (int t = 0; t < TT; ++t) {
      unsigned tgt = t+1;
      // x-half A prefetch (read-only, plain cached) BEFORE waiting on h(t-1)
      s8v xa0[8], xa1[8];
      {
        int kb = wave * 256;
        const s8v* e0p = (const s8v*)(encb + (size_t)tok[t*BB + r]*NHID + kb);
        const s8v* e1p = (const s8v*)(encb + (size_t)tok[t*BB + 16 + r]*NHID + kb);
        #pragma unroll
        for (int i=0;i<8;i++){ xa0[i]=e0p[q+4*i]; xa1[i]=e1p[q+4*i]; }
      }
      if (t && lane < 17){
        int idx = (8<<6) + ((lane<16) ? (wave*16 + lane) : tile);
        poll1(F, idx, t);
      }
      int row = tid>>3, col = (tid&7)*2;
      size_t off = (size_t)row*NHID + j0 + col;
      const float* hfb = t ? h_f : h0f;
      float hp0, hp1; ld_f2(hfb + off, hp0, hp1);
      const unsigned short* hb = t ? h_bf : h0b;
      int kb = wave*256;
      s8v ha0[8], ha1[8];
      coh_ld16(hb + (size_t)r*NHID + kb + q*8,
               hb + (size_t)(16+r)*NHID + kb + q*8, ha0, ha1);
      f4v zz = {0.f,0.f,0.f,0.f};
      f4v aC0=zz,aC1=zz,aH0=zz,aH1=zz;
      #pragma unroll
      for (int i=0;i<8;i++){
        aC0=MFMA(xa0[i],BX.c[i],aC0); aC1=MFMA(xa1[i],BX.c[i],aC1);
        aH0=MFMA(xa0[i],BX.h[i],aH0); aH1=MFMA(xa1[i],BX.h[i],aH1);
      }
      #pragma unroll
      for (int i=0;i<8;i++){
        aC0=MFMA(ha0[i],BH.c[i],aC0); aC1=MFMA(ha1[i],BH.c[i],aC1);
        aH0=MFMA(ha0[i],BH.h[i],aH0); aH1=MFMA(ha1[i],BH.h[i],aH1);
      }
      #pragma unroll
      for (int i=0;i<4;i++){
        red[((wave*4+0)*32 + q*4+i)*16 + r]    = aC0[i];
        red[((wave*4+0)*32 + 16+q*4+i)*16 + r] = aC1[i];
        red[((wave*4+1)*32 + q*4+i)*16 + r]    = aH0[i];
        red[((wave*4+1)*32 + 16+q*4+i)*16 + r] = aH1[i];
      }
      __syncthreads();
      float cs0=0,cs1=0,hs0=0,hs1=0;
      #pragma unroll
      for (int w2=0; w2<4; w2++){
        cs0 += red[((w2*4+0)*32+row)*16+col];
        cs1 += red[((w2*4+0)*32+row)*16+col+1];
        hs0 += red[((w2*4+1)*32+row)*16+col];
        hs1 += red[((w2*4+1)*32+row)*16+col+1];
      }
      float v0 = hp0 + sigf(cs0)*(tanhf(hs0)-hp0);
      float v1 = hp1 + sigf(cs1)*(tanhf(hs1)-hp1);
      st_wt64(&st_f[off], packf2(v0, v1));
      unsigned pk = (unsigned)f2bf(v0) | ((unsigned)f2bf(v1)<<16);
      st_wt32((unsigned*)(st_bf + off), pk);
      signal(F, 0, tile, tgt);
      // ---- e3 (identity, pred s1, out s4) ----
      do_edge_reg(B3, st_f, st_bf, red, F, 1, 4, 3, j0, tile, tgt, wave, q, r, tid);
    }
  } else if (grp == 1) {
    B8 B0; load_b8(Wt, 2, j0, r, wave*256, q, B0);   // e0: sigmoid, s0->s1
    B8 B4; load_b8(Wt, 6, j0, r, wave*256, q, B4);   // e4: tanh,    s2->s5
    for (int t = 0; t < TT; ++t) {
      unsigned tgt = t+1;
      do_edge_reg(B0, st_f, st_bf, red, F, 0, 1, 0, j0, tile, tgt, wave, q, r, tid);
      do_edge_reg(B4, st_f, st_bf, red, F, 2, 5, 2, j0, tile, tgt, wave, q, r, tid);
    }
  } else if (grp == 2) {
    B8 B1; load_b8(Wt, 3, j0, r, wave*256, q, B1);   // e1: relu, s1->s2
    B8 B6; load_b8(Wt, 8, j0, r, wave*256, q, B6);   // e6: tanh, s3->s7
    for (int t = 0; t < TT; ++t) {
      unsigned tgt = t+1;
      do_edge_reg(B1, st_f, st_bf, red, F, 1, 2, 1, j0, tile, tgt, wave, q, r, tid);
      do_edge_reg(B6, st_f, st_bf, red, F, 3, 7, 2, j0, tile, tgt, wave, q, r, tid);
    }
  } else {
    B8 B2; load_b8(Wt, 4, j0, r, wave*256, q, B2);   // e2: relu, s1->s3
    B8 B5; load_b8(Wt, 7, j0, r, wave*256, q, B5);   // e5: sigmoid, s5->s6
    B8 B7; load_b8(Wt, 9, j0, r, wave*256, q, B7);   // e7: relu,    s5->s8
    for (int t = 0; t < TT; ++t) {
      unsigned tgt = t+1;
      // ---- e2 (relu, pred s1, out s3) ----
      do_edge_reg(B2, st_f, st_bf, red, F, 1, 3, 1, j0, tile, tgt, wave, q, r, tid);
      // ---- fused e5 (sigmoid) + e7 (relu), pred s5; compute mean h ----
      if (lane < 19){
        int idx = (lane<16) ? ((5<<6) + wave*16 + lane)
                : (lane==16) ? ((4<<6)+tile)
                : (lane==17) ? ((5<<6)+tile) : ((7<<6)+tile);
        poll1(F, idx, tgt);
      }
      {
        int row = tid>>3, col = (tid&7)*2;
        size_t off = (size_t)row*NHID + j0 + col;
        float s1a,s1b,s2a,s2b,s3a,s3b,s4a,s4b,s5a,s5b,s7a,s7b;
        ld_f2(st_f + (size_t)1*BN + off, s1a, s1b);
        ld_f2(st_f + (size_t)2*BN + off, s2a, s2b);
        ld_f2(st_f + (size_t)3*BN + off, s3a, s3b);
        ld_f2(st_f + (size_t)4*BN + off, s4a, s4b);
        ld_f2(st_f + (size_t)5*BN + off, s5a, s5b);
        ld_f2(st_f + (size_t)7*BN + off, s7a, s7b);
        const unsigned short* spb = st_bf + (size_t)5*BN;
        int kb = wave*256;
        s8v a0[8], a1[8];
        coh_ld16(spb + (size_t)r*NHID + kb + q*8,
                 spb + (size_t)(16+r)*NHID + kb + q*8, a0, a1);
        f4v zz = {0.f,0.f,0.f,0.f};
        f4v c50=zz,c51=zz,h50=zz,h51=zz,c70=zz,c71=zz,h70=zz,h71=zz;
        #pragma unroll
        for (int i=0;i<8;i++){
          c50=MFMA(a0[i],B5.c[i],c50); c51=MFMA(a1[i],B5.c[i],c51);
          h50=MFMA(a0[i],B5.h[i],h50); h51=MFMA(a1[i],B5.h[i],h51);
          c70=MFMA(a0[i],B7.c[i],c70); c71=MFMA(a1[i],B7.c[i],c71);
          h70=MFMA(a0[i],B7.h[i],h70); h71=MFMA(a1[i],B7.h[i],h71);
        }
        #pragma unroll
        for (int i=0;i<4;i++){
          red[((wave*4+0)*32 + q*4+i)*16 + r]    = c50[i];
          red[((wave*4+0)*32 + 16+q*4+i)*16 + r] = c51[i];
          red[((wave*4+1)*32 + q*4+i)*16 + r]    = h50[i];
          red[((wave*4+1)*32 + 16+q*4+i)*16 + r] = h51[i];
          red[((wave*4+2)*32 + q*4+i)*16 + r]    = c70[i];
          red[((wave*4+2)*32 + 16+q*4+i)*16 + r] = c71[i];
          red[((wave*4+3)*32 + q*4+i)*16 + r]    = h70[i];
          red[((wave*4+3)*32 + 16+q*4+i)*16 + r] = h71[i];
        }
        __syncthreads();
        float a5c[2]={0,0}, a5h[2]={0,0}, a7c[2]={0,0}, a7h[2]={0,0};
        #pragma unroll
        for (int w2=0; w2<4; w2++){
          #pragma unroll
          for (int u=0; u<2; u++){
            a5c[u] += red[((w2*4+0)*32+row)*16+col+u];
            a5h[u] += red[((w2*4+1)*32+row)*16+col+u];
            a7c[u] += red[((w2*4+2)*32+row)*16+col+u];
            a7h[u] += red[((w2*4+3)*32+row)*16+col+u];
          }
        }
        float s5v[2] = {s5a, s5b};
        float o1[2] = {s1a, s1b}, o2[2] = {s2a, s2b}, o3[2] = {s3a, s3b};
        float o4[2] = {s4a, s4b}, o7[2] = {s7a, s7b};
        float hv[2];
        #pragma unroll
        for (int u=0; u<2; u++){
          float s5j = s5v[u];
          float s6 = s5j + sigf(a5c[u])*(sigf(a5h[u]) - s5j);
          float s8 = s5j + sigf(a7c[u])*(fmaxf(a7h[u],0.f) - s5j);
          float sum = o1[u] + o2[u] + o3[u] + o4[u]
                    + s5j + s6 + o7[u] + s8;
          hv[u] = 0.125f * sum;
        }
        st_wt64(&h_f[off], packf2(hv[0], hv[1]));
        unsigned pk = (unsigned)f2bf(hv[0]) | ((unsigned)f2bf(hv[1])<<16);
        st_wt32((unsigned*)(h_bf + off), pk);
        *(unsigned*)(hid_bf + (size_t)t*BN + off) = pk;   // consumed post-kernel
        signal(F, 8, tile, tgt);
      }
    }
  }
}

// ---------------- decoder ----------------
// v5: XCD-locality remap. Each XCD (blockIdx%8 heuristic) sweeps one 16-row-
// tile A-band (2 MB, L2-resident) bn-major; each B col-tile (128 KB) is
// reused 16x from L2. Traffic ~2.6 GB -> ~150 MB. Perf-only heuristic:
// wrong XCD mapping only costs locality, never correctness.

__global__ __launch_bounds__(256) void k_decoder(
    const unsigned short* __restrict__ Hb, const unsigned short* __restrict__ Wb,
    float* __restrict__ out)
{
  int L = blockIdx.x;
  int xcd = L & 7, i = L >> 3;          // i: 0..1279
  int band = i / 320;                   // 4 bands of 16 bm-tiles
  int r2 = i % 320;
  int bnIdx = r2 >> 4, bmi = r2 & 15;
  int bn_t = xcd + 8*bnIdx;             // col tile 0..159
  if (bn_t >= 157) return;
  int bm_t = band*16 + bmi;             // row tile 0..63
  int wave = threadIdx.x >> 6, lane = threadIdx.x & 63;
  int q = lane >> 4, r = lane & 15;
  int bm = bm_t*64 + (wave>>1)*32;
  int bn = bn_t*64 + (wave&1)*32;
  f4v z = {0.f,0.f,0.f,0.f};
  f4v acc00=z, acc01=z, acc10=z, acc11=z;
  const s8v* a0p = (const s8v*)(Hb + (size_t)(bm + r)*NHID);
  const s8v* a1p = (const s8v*)(Hb + (size_t)(bm + 16 + r)*NHID);
  int n0 = bn + r, n1 = bn + 16 + r;
  const s8v* b0p = (const s8v*)(Wb + (size_t)(n0 < NTOK ? n0 : 0)*NHID);
  const s8v* b1p = (const s8v*)(Wb + (size_t)(n1 < NTOK ? n1 : 0)*NHID);
  #pragma unroll 4
  for (int v = q; v < 128; v += 4) {
    s8v a0 = a0p[v], a1 = a1p[v], b0 = b0p[v], b1 = b1p[v];
    acc00 = MFMA(a0, b0, acc00); acc10 = MFMA(a1, b0, acc10);
    acc01 = MFMA(a0, b1, acc01); acc11 = MFMA(a1, b1, acc11);
  }
  #pragma unroll
  for (int ni=0; ni<2; ni++){
    int col = bn + ni*16 + r;
    if (col >= NTOK) continue;
    #pragma unroll
    for (int mi=0; mi<2; mi++){
      f4v a = (mi==0) ? (ni==0 ? acc00 : acc01) : (ni==0 ? acc10 : acc11);
      #pragma unroll
      for (int t4=0; t4<4; t4++){
        int row = bm + mi*16 + q*4 + t4;
        out[(size_t)row*NTOK + col] = a[t4];
      }
    }
  }
}

__global__ __launch_bounds__(256) void k_logsoftmax(
    float* __restrict__ logits, const float* __restrict__ bias)
{
  size_t row = blockIdx.x;
  float* p = logits + row * NTOK;
  float v[40];
  float mx = -1e30f;
  #pragma unroll
  for (int i=0;i<40;i++){
    int c = threadIdx.x + (i<<8);
    float x = (c < NTOK) ? (p[c] + bias[c]) : -1e30f;
    v[i] = x; mx = fmaxf(mx, x);
  }
  #pragma unroll
  for (int off=32; off>0; off>>=1) mx = fmaxf(mx, __shfl_down(mx, off));
  __shared__ float red[4], red2[4];
  int wv = threadIdx.x>>6, ln = threadIdx.x&63;
  if (ln==0) red[wv] = mx;
  __syncthreads();
  mx = fmaxf(fmaxf(red[0],red[1]), fmaxf(red[2],red[3]));
  float s = 0.f;
  #pragma unroll
  for (int i=0;i<40;i++) s += __expf(v[i] - mx);
  #pragma unroll
  for (int off=32; off>0; off>>=1) s += __shfl_down(s, off);
  if (ln==0) red2[wv] = s;
  __syncthreads();
  s = red2[0]+red2[1]+red2[2]+red2[3];
  float lse = mx + __logf(s);
  #pragma unroll
  for (int i=0;i<40;i++){
    int c = threadIdx.x + (i<<8);
    if (c < NTOK) p[c] = v[i] - lse;
  }
}

__global__ void k_copy(const float* __restrict__ src, float* __restrict__ dst, int n){
  int i = blockIdx.x*blockDim.x + threadIdx.x;
  if (i < n) dst[i] = src[i];
}

// ---------------- launch ----------------

extern "C" void kernel_launch(void* const* d_in, const int* in_sizes, int n_in,
                              void* d_out, int out_size, void* d_ws, size_t ws_size,
                              hipStream_t stream) {
  const int*   tok  = (const int*)d_in[0];
  const float* h0   = (const float*)d_in[1];
  const float* encw = (const float*)d_in[2];
  const float* W0   = (const float*)d_in[3];
  const float* Ws   = (const float*)d_in[4];
  const float* decb = (const float*)d_in[5];
  float* out = (float*)d_out;

  char* w = (char*)d_ws;
  unsigned short* Wt      = (unsigned short*)w; w += (size_t)10*WMAT*2;
  unsigned short* encw_bf = (unsigned short*)w; w += (size_t)NTOK*NHID*2;
  unsigned short* h0_bf   = (unsigned short*)w; w += (size_t)BN*2;
  unsigned short* hid_bf  = (unsigned short*)w; w += (size_t)TT*BN*2;
  float*          st_f    = (float*)w;          w += (size_t)9*BN*4;
  unsigned short* st_bf   = (unsigned short*)w; w += (size_t)9*BN*2;
  float*          h_f     = (float*)w;          w += (size_t)BN*4;
  unsigned short* h_bf    = (unsigned short*)w; w += (size_t)BN*2;
  unsigned*       flags   = (unsigned*)w;       w += (size_t)576*FSTRIDE*4;

  k_zero<<<36, 256, 0, stream>>>(flags, 576*FSTRIDE);
  k_transpose_cvt<<<dim3(64,32,10), 256, 0, stream>>>(W0, Ws, Wt);
  k_cvt<<<4096, 256, 0, stream>>>(encw, encw_bf, NTOK*NHID);
  k_cvt<<<128, 256, 0, stream>>>(h0, h0_bf, BN);

  k_recur<<<256, 256, 0, stream>>>(tok, h0, encw_bf, Wt, h0_bf,
                                   st_f, st_bf, h_f, h_bf, hid_bf, flags);

  k_decoder<<<10240, 256, 0, stream>>>(hid_bf, encw_bf, out);
  k_logsoftmax<<<TT*BB, 256, 0, stream>>>(out, decb);
  k_copy<<<128, 256, 0, stream>>>(h_f, out + (size_t)TT*BB*NTOK, BN);
}